// Round 5
// baseline (572.156 us; speedup 1.0000x reference)
//
#include <hip/hip_runtime.h>
#include <cstdint>
#include <cstddef>

#define NN 262144
#define EE 2097152
#define BB 64
#define CCROSS 32
#define PCC 128
#define PP 2048
#define NBUCK 256
#define BCAP 12288

typedef _Float16 f16;
typedef __attribute__((ext_vector_type(2))) _Float16 f16x2;
typedef __attribute__((ext_vector_type(4))) _Float16 f16x4;
typedef __attribute__((ext_vector_type(8))) _Float16 f16x8;
typedef __attribute__((ext_vector_type(4))) float f32x4;

static __device__ __forceinline__ float lrelu(float x, float s) { return x > 0.f ? x : s * x; }

#if __has_builtin(__builtin_amdgcn_fdot2)
static __device__ __forceinline__ float dot2f(unsigned x, unsigned w, float c) {
    return __builtin_amdgcn_fdot2(__builtin_bit_cast(f16x2, x), __builtin_bit_cast(f16x2, w), c, false);
}
#else
static __device__ __forceinline__ float dot2f(unsigned x, unsigned w, float c) {
    f16x2 a = __builtin_bit_cast(f16x2, x);
    f16x2 b = __builtin_bit_cast(f16x2, w);
    return fmaf((float)a[0], (float)b[0], fmaf((float)a[1], (float)b[1], c));
}
#endif

// ---------------- bucketed CSR build ----------------
__global__ __launch_bounds__(256) void bucket_a_k(const int* __restrict__ src, const int* __restrict__ dst,
                                                  unsigned* __restrict__ buckets, int* __restrict__ gcnt) {
    __shared__ int hist[NBUCK];
    __shared__ int base[NBUCK];
    __shared__ unsigned short rankbuf[8192];
    const int tid = threadIdx.x;
    const int e0 = blockIdx.x * 8192;
    hist[tid] = 0;
    __syncthreads();
    for (int i = tid; i < 8192; i += 256) {
        int d = dst[e0 + i];
        rankbuf[i] = (unsigned short)atomicAdd(&hist[d >> 10], 1);
    }
    __syncthreads();
    base[tid] = tid * BCAP + atomicAdd(&gcnt[tid], hist[tid]);
    __syncthreads();
    for (int i = tid; i < 8192; i += 256) {
        int s = src[e0 + i];
        int d = dst[e0 + i];
        int b = d >> 10;
        buckets[base[b] + rankbuf[i]] = ((unsigned)s << 10) | (unsigned)(d & 1023);
    }
}

__global__ void bucket_scan_k(const int* __restrict__ gcnt, int* __restrict__ bbase, int* __restrict__ rp) {
    __shared__ int tmp[256];
    int tid = threadIdx.x;
    int v = gcnt[tid];
    tmp[tid] = v;
    __syncthreads();
    for (int off = 1; off < 256; off <<= 1) {
        int t = (tid >= off) ? tmp[tid - off] : 0;
        __syncthreads();
        tmp[tid] += t;
        __syncthreads();
    }
    bbase[tid] = tmp[tid] - v;
    if (tid == 0) rp[NN] = EE;
}

__global__ __launch_bounds__(256) void bucket_b_k(const unsigned* __restrict__ buckets, const int* __restrict__ gcnt,
                                                  const int* __restrict__ bbase, int* __restrict__ rp,
                                                  float* __restrict__ dinv, int* __restrict__ col) {
    __shared__ int cnt[1024];
    __shared__ int scan[1024];
    __shared__ int wsum[256];
    const int b = blockIdx.x;
    const int tid = threadIdx.x;
    int n = gcnt[b];
    if (n > BCAP) n = BCAP;
    const unsigned* eb = buckets + (size_t)b * BCAP;
    const int gb = bbase[b];
    for (int i = tid; i < 1024; i += 256) cnt[i] = 0;
    __syncthreads();
    for (int i = tid; i < n; i += 256) atomicAdd(&cnt[eb[i] & 1023], 1);
    __syncthreads();
    int b4 = tid * 4;
    int c0 = cnt[b4], c1 = cnt[b4 + 1], c2 = cnt[b4 + 2], c3 = cnt[b4 + 3];
    int tsum = c0 + c1 + c2 + c3;
    wsum[tid] = tsum;
    __syncthreads();
    for (int off = 1; off < 256; off <<= 1) {
        int t = (tid >= off) ? wsum[tid - off] : 0;
        __syncthreads();
        wsum[tid] += t;
        __syncthreads();
    }
    int excl = wsum[tid] - tsum;
    scan[b4] = excl;
    scan[b4 + 1] = excl + c0;
    scan[b4 + 2] = excl + c0 + c1;
    scan[b4 + 3] = excl + c0 + c1 + c2;
    int vbase = b * 1024 + b4;
    rp[vbase + 0] = gb + scan[b4 + 0];
    rp[vbase + 1] = gb + scan[b4 + 1];
    rp[vbase + 2] = gb + scan[b4 + 2];
    rp[vbase + 3] = gb + scan[b4 + 3];
    dinv[vbase + 0] = rsqrtf((float)(c0 + 1));
    dinv[vbase + 1] = rsqrtf((float)(c1 + 1));
    dinv[vbase + 2] = rsqrtf((float)(c2 + 1));
    dinv[vbase + 3] = rsqrtf((float)(c3 + 1));
    __syncthreads();
    for (int i = tid; i < 1024; i += 256) cnt[i] = 0;
    __syncthreads();
    for (int i = tid; i < n; i += 256) {
        unsigned p = eb[i];
        int dl = p & 1023;
        int r = atomicAdd(&cnt[dl], 1);
        col[gb + scan[dl] + r] = (int)(p >> 10);
    }
}

// ---------------- z-prep ----------------
__global__ void zprep_k(const float* __restrict__ x, const float* __restrict__ dinv, f16* __restrict__ z) {
    int v = blockIdx.x * 256 + threadIdx.x;
    if (v >= NN) return;
    float dv = dinv[v];
    const float* xr = x + (size_t)v * 19;
    float vv[20];
#pragma unroll
    for (int k = 0; k < 19; k++) vv[k] = dv * xr[k];
    vv[19] = 0.f;
    f16x4* zr = (f16x4*)(z + (size_t)v * 32);
#pragma unroll
    for (int c = 0; c < 5; c++) {
        f16x4 t = {(f16)vv[4 * c], (f16)vv[4 * c + 1], (f16)vv[4 * c + 2], (f16)vv[4 * c + 3]};
        zr[c] = t;
    }
    f16x4 zz = {(f16)0.f, (f16)0.f, (f16)0.f, (f16)0.f};
#pragma unroll
    for (int c = 5; c < 8; c++) zr[c] = zz;
}

// ---------------- fused agg (64B fp16 rows) + gemm, wide-gather version ----------------
#define ZSTR1 36
template <int KINR, int KOUT, int ACT>
__global__ __launch_bounds__(256) void fused_agg_gemm_k(const f16* __restrict__ z, const int* __restrict__ rp,
                                                        const int* __restrict__ col, const float* __restrict__ Wg,
                                                        const float* __restrict__ dinv, const float* __restrict__ bias,
                                                        f16* __restrict__ zout) {
    constexpr int NO = KOUT / 4;
    __shared__ float Wl[32 * KOUT];
    __shared__ float zrow[64 * ZSTR1];
    const int tid = threadIdx.x;
    for (int i = tid; i < 32 * KOUT; i += 256) Wl[i] = (i < KINR * KOUT) ? Wg[i] : 0.f;

    const int r = tid >> 2;
    const int idx = tid & 3;
    const int v = blockIdx.x * 64 + r;
    const f16x8* z8 = (const f16x8*)z;
    f16x8 a = z8[(size_t)v * 4 + idx];
    float acc8[8];
#pragma unroll
    for (int j = 0; j < 8; j++) acc8[j] = (float)a[j];
    int st = rp[v], e = rp[v + 1];
    int i = st;
    for (; i + 4 <= e; i += 4) {
        int u0 = col[i], u1 = col[i + 1], u2 = col[i + 2], u3 = col[i + 3];
        f16x8 a0 = z8[(size_t)u0 * 4 + idx];
        f16x8 a1 = z8[(size_t)u1 * 4 + idx];
        f16x8 a2 = z8[(size_t)u2 * 4 + idx];
        f16x8 a3 = z8[(size_t)u3 * 4 + idx];
#pragma unroll
        for (int j = 0; j < 8; j++)
            acc8[j] += ((float)a0[j] + (float)a1[j]) + ((float)a2[j] + (float)a3[j]);
    }
    for (; i < e; i++) {
        f16x8 aa = z8[(size_t)col[i] * 4 + idx];
#pragma unroll
        for (int j = 0; j < 8; j++) acc8[j] += (float)aa[j];
    }
    float4 s0, s1;
    s0.x = acc8[0]; s0.y = acc8[1]; s0.z = acc8[2]; s0.w = acc8[3];
    s1.x = acc8[4]; s1.y = acc8[5]; s1.z = acc8[6]; s1.w = acc8[7];
    *(float4*)&zrow[r * ZSTR1 + idx * 8] = s0;
    *(float4*)&zrow[r * ZSTR1 + idx * 8 + 4] = s1;
    __syncthreads();

    float acc[NO];
#pragma unroll
    for (int j = 0; j < NO; j++) acc[j] = 0.f;
#pragma unroll 4
    for (int k = 0; k < 32; k++) {
        float zv = zrow[r * ZSTR1 + k];
        const float* wr = Wl + k * KOUT + NO * idx;
#pragma unroll
        for (int j = 0; j < NO; j++) acc[j] = fmaf(zv, wr[j], acc[j]);
    }
    float dv = dinv[v];
    f16 hv[NO];
#pragma unroll
    for (int j = 0; j < NO; j++) {
        float o = dv * acc[j] + bias[NO * idx + j];
        o = (ACT == 0) ? fmaxf(o, 0.f) : lrelu(o, 0.01f);
        hv[j] = (f16)(o * dv);
    }
    if constexpr (NO == 8) {
        f16x8 h = {hv[0], hv[1], hv[2], hv[3], hv[4], hv[5], hv[6], hv[7]};
        *(f16x8*)(zout + (size_t)v * KOUT + NO * idx) = h;
    } else {
        f16x8 h0 = {hv[0], hv[1], hv[2], hv[3], hv[4], hv[5], hv[6], hv[7]};
        f16x8 h1 = {hv[8], hv[9], hv[10], hv[11], hv[12], hv[13], hv[14], hv[15]};
        f16x8* yo = (f16x8*)(zout + (size_t)v * KOUT + NO * idx);
        yo[0] = h0; yo[1] = h1;
    }
}

// ---------------- pack W (64x64 fp32 row-major k x n) into fp16 B-fragment order ----------------
__global__ void pack_w_k(const float* __restrict__ W, f16* __restrict__ out) {
    int o = blockIdx.x * 256 + threadIdx.x;
    if (o >= 4096) return;
    int frag = o >> 9;
    int kt = frag >> 2;
    int c = frag & 3;
    int idx = o & 511;
    int l = idx >> 3;
    int j = idx & 7;
    int k = kt * 32 + ((l >> 4) << 3) + j;
    int n = 16 * c + (l & 15);
    out[o] = (f16)W[k * 64 + n];
}

// ---------------- pack conv weights to f16, k-major (pairs along in-ch for dot2) ----------------
__global__ void pack_c2_k(const float* __restrict__ W, f16* __restrict__ out) {
    int o = blockIdx.x * 256 + threadIdx.x;  // 64*96
    if (o >= 64 * 96) return;
    int ch = o / 96, r = o - ch * 96;
    int k = r >> 5, ci = r & 31;
    out[o] = (f16)W[ch * 96 + ci * 3 + k];
}

__global__ void pack_c3_k(const float* __restrict__ W, f16* __restrict__ out) {
    int o = blockIdx.x * 256 + threadIdx.x;  // 64*192
    if (o >= 64 * 192) return;
    int ch = o / 192, r = o - ch * 192;
    int k = r >> 6, ci = r & 63;
    out[o] = (f16)W[ch * 192 + ci * 3 + k];
}

// ---------------- fused: edge-parallel agg(z3) -> LDS f32; h3; xw = h3@Wg1; es/ed ----------------
// Gather: 32 slots x 8 feat-lanes; each slot walks a contiguous ~16-edge chunk of the block's
// contiguous edge range [rp[v0], rp[v0+64]), segmented by dst via LDS rp copy; register
// accumulation per dst-run, f32 LDS atomicAdd flush (atomics only matter at chunk boundaries).
#define HSTR 72
#define Z32S 68
__global__ __launch_bounds__(256) void gemm3_gat_k(const f16* __restrict__ y, const int* __restrict__ rp,
                                                   const int* __restrict__ col, const f16* __restrict__ w3p,
                                                   const float* __restrict__ dinv, const float* __restrict__ b3,
                                                   const f16* __restrict__ wgp, const float* __restrict__ av,
                                                   const float* __restrict__ ad, f16* __restrict__ xw,
                                                   float* __restrict__ es, float* __restrict__ ed) {
    __shared__ float zin32[64 * Z32S];  // f32 agg accumulators; reused as hh after conversion
    __shared__ f16 zin[64 * HSTR];
    __shared__ int rpl[65];
    f16* hh = (f16*)zin32;

    const int tid = threadIdx.x;
    const int v0 = blockIdx.x * 64;
    const f16x8* y8 = (const f16x8*)y;

    if (tid < 65) rpl[tid] = rp[v0 + tid];
    {   // self rows seed the f32 tile
        const int row = tid >> 2, qq = tid & 3;
        const f16x8* yp = y8 + (size_t)(v0 + row) * 8 + qq * 2;
        f16x8 s0 = yp[0], s1 = yp[1];
        float* zr = &zin32[row * Z32S + qq * 16];
#pragma unroll
        for (int j = 0; j < 8; j++) { zr[j] = (float)s0[j]; zr[8 + j] = (float)s1[j]; }
    }
    __syncthreads();

    {   // edge-parallel segmented gather
        const int slot = tid >> 3;
        const int f = tid & 7;
        const int sE = rpl[0], eE = rpl[64];
        const int chunk = (eE - sE + 31) >> 5;
        int i = sE + slot * chunk;
        const int iend = min(i + chunk, eE);
        if (i < iend) {
            int lo = 0, hi = 64;
            while (hi - lo > 1) { int mid = (lo + hi) >> 1; if (i >= rpl[mid]) lo = mid; else hi = mid; }
            int r = lo;
            while (i < iend) {
                while (i >= rpl[r + 1]) r++;
                const int rend = min(rpl[r + 1], iend);
                float acc[8];
#pragma unroll
                for (int j = 0; j < 8; j++) acc[j] = 0.f;
                for (; i + 2 <= rend; i += 2) {
                    int u0 = col[i], u1 = col[i + 1];
                    f16x8 a0 = y8[(size_t)u0 * 8 + f];
                    f16x8 a1 = y8[(size_t)u1 * 8 + f];
#pragma unroll
                    for (int j = 0; j < 8; j++) acc[j] += (float)a0[j] + (float)a1[j];
                }
                for (; i < rend; i++) {
                    f16x8 a = y8[(size_t)col[i] * 8 + f];
#pragma unroll
                    for (int j = 0; j < 8; j++) acc[j] += (float)a[j];
                }
                float* zr = &zin32[r * Z32S + f * 8];
#pragma unroll
                for (int j = 0; j < 8; j++) atomicAdd(&zr[j], acc[j]);
            }
        }
    }
    __syncthreads();

    {   // convert f32 tile -> f16 MFMA tile
        const int row = tid >> 2, qq = tid & 3;
        const float* zr = &zin32[row * Z32S + qq * 16];
        f16x8 o0, o1;
#pragma unroll
        for (int j = 0; j < 8; j++) { o0[j] = (f16)zr[j]; o1[j] = (f16)zr[8 + j]; }
        *(f16x8*)&zin[row * HSTR + qq * 16] = o0;
        *(f16x8*)&zin[row * HSTR + qq * 16 + 8] = o1;
    }
    __syncthreads();

    const int w = tid >> 6;
    const int l = tid & 63;
    const int m = l & 15;
    const int q = l >> 4;
    const int r0 = 16 * w;

    f32x4 acc0 = {0.f, 0.f, 0.f, 0.f}, acc1 = acc0, acc2 = acc0, acc3 = acc0;
#pragma unroll
    for (int kt = 0; kt < 2; kt++) {
        f16x8 afrag = *(const f16x8*)&zin[(r0 + m) * HSTR + kt * 32 + q * 8];
        f16x8 b0 = *(const f16x8*)&w3p[((kt * 4 + 0) << 9) + l * 8];
        f16x8 b1 = *(const f16x8*)&w3p[((kt * 4 + 1) << 9) + l * 8];
        f16x8 b2 = *(const f16x8*)&w3p[((kt * 4 + 2) << 9) + l * 8];
        f16x8 b3f = *(const f16x8*)&w3p[((kt * 4 + 3) << 9) + l * 8];
        acc0 = __builtin_amdgcn_mfma_f32_16x16x32_f16(afrag, b0, acc0, 0, 0, 0);
        acc1 = __builtin_amdgcn_mfma_f32_16x16x32_f16(afrag, b1, acc1, 0, 0, 0);
        acc2 = __builtin_amdgcn_mfma_f32_16x16x32_f16(afrag, b2, acc2, 0, 0, 0);
        acc3 = __builtin_amdgcn_mfma_f32_16x16x32_f16(afrag, b3f, acc3, 0, 0, 0);
    }
    {
        float dv0 = dinv[v0 + r0 + q * 4 + 0];
        float dv1 = dinv[v0 + r0 + q * 4 + 1];
        float dv2 = dinv[v0 + r0 + q * 4 + 2];
        float dv3 = dinv[v0 + r0 + q * 4 + 3];
#pragma unroll
        for (int c = 0; c < 4; c++) {
            const f32x4* ac = (c == 0) ? &acc0 : (c == 1) ? &acc1 : (c == 2) ? &acc2 : &acc3;
            float bb = b3[16 * c + m];
            hh[(r0 + q * 4 + 0) * HSTR + 16 * c + m] = (f16)lrelu(dv0 * (*ac)[0] + bb, 0.01f);
            hh[(r0 + q * 4 + 1) * HSTR + 16 * c + m] = (f16)lrelu(dv1 * (*ac)[1] + bb, 0.01f);
            hh[(r0 + q * 4 + 2) * HSTR + 16 * c + m] = (f16)lrelu(dv2 * (*ac)[2] + bb, 0.01f);
            hh[(r0 + q * 4 + 3) * HSTR + 16 * c + m] = (f16)lrelu(dv3 * (*ac)[3] + bb, 0.01f);
        }
    }
    __syncthreads();

    acc0 = (f32x4){0.f, 0.f, 0.f, 0.f}; acc1 = acc0; acc2 = acc0; acc3 = acc0;
#pragma unroll
    for (int kt = 0; kt < 2; kt++) {
        f16x8 afrag = *(const f16x8*)&hh[(r0 + m) * HSTR + kt * 32 + q * 8];
        f16x8 b0 = *(const f16x8*)&wgp[((kt * 4 + 0) << 9) + l * 8];
        f16x8 b1 = *(const f16x8*)&wgp[((kt * 4 + 1) << 9) + l * 8];
        f16x8 b2 = *(const f16x8*)&wgp[((kt * 4 + 2) << 9) + l * 8];
        f16x8 b3f = *(const f16x8*)&wgp[((kt * 4 + 3) << 9) + l * 8];
        acc0 = __builtin_amdgcn_mfma_f32_16x16x32_f16(afrag, b0, acc0, 0, 0, 0);
        acc1 = __builtin_amdgcn_mfma_f32_16x16x32_f16(afrag, b1, acc1, 0, 0, 0);
        acc2 = __builtin_amdgcn_mfma_f32_16x16x32_f16(afrag, b2, acc2, 0, 0, 0);
        acc3 = __builtin_amdgcn_mfma_f32_16x16x32_f16(afrag, b3f, acc3, 0, 0, 0);
    }
    {
        float e1[4] = {0.f, 0.f, 0.f, 0.f}, e2[4] = {0.f, 0.f, 0.f, 0.f};
#pragma unroll
        for (int c = 0; c < 4; c++) {
            const f32x4* ac = (c == 0) ? &acc0 : (c == 1) ? &acc1 : (c == 2) ? &acc2 : &acc3;
            float a1 = av[16 * c + m];
            float d1 = ad[16 * c + m];
#pragma unroll
            for (int reg = 0; reg < 4; reg++) {
                float g = (*ac)[reg];
                e1[reg] = fmaf(g, a1, e1[reg]);
                e2[reg] = fmaf(g, d1, e2[reg]);
                xw[(size_t)(v0 + r0 + q * 4 + reg) * 64 + 16 * c + m] = (f16)g;
            }
        }
#pragma unroll
        for (int reg = 0; reg < 4; reg++) {
            e1[reg] += __shfl_xor(e1[reg], 1); e1[reg] += __shfl_xor(e1[reg], 2);
            e1[reg] += __shfl_xor(e1[reg], 4); e1[reg] += __shfl_xor(e1[reg], 8);
            e2[reg] += __shfl_xor(e2[reg], 1); e2[reg] += __shfl_xor(e2[reg], 2);
            e2[reg] += __shfl_xor(e2[reg], 4); e2[reg] += __shfl_xor(e2[reg], 8);
        }
        if (m == 0) {
#pragma unroll
            for (int reg = 0; reg < 4; reg++) {
                es[v0 + r0 + q * 4 + reg] = e1[reg];
                ed[v0 + r0 + q * 4 + reg] = e2[reg];
            }
        }
    }
}

// ---------------- GAT edge softmax weights, normalization folded in ----------------
__global__ void gat_w_k(const float* __restrict__ es, const float* __restrict__ ed,
                        const int* __restrict__ rp, const int* __restrict__ col,
                        f16* __restrict__ ewi, float* __restrict__ wsi) {
    int v = blockIdx.x * 256 + threadIdx.x;
    if (v >= NN) return;
    float edv = ed[v];
    float eself = lrelu(es[v] + edv, 0.2f);
    float m = eself;
    int s = rp[v], e = rp[v + 1];
    int i = s;
    float lg[32];
    for (; i + 4 <= e; i += 4) {
        int u0 = col[i], u1 = col[i + 1], u2 = col[i + 2], u3 = col[i + 3];
        float t0 = lrelu(es[u0] + edv, 0.2f);
        float t1 = lrelu(es[u1] + edv, 0.2f);
        float t2 = lrelu(es[u2] + edv, 0.2f);
        float t3 = lrelu(es[u3] + edv, 0.2f);
        int k = i - s;
        if (k + 3 < 32) { lg[k] = t0; lg[k + 1] = t1; lg[k + 2] = t2; lg[k + 3] = t3; }
        m = fmaxf(m, fmaxf(fmaxf(t0, t1), fmaxf(t2, t3)));
    }
    for (; i < e; i++) {
        float t = lrelu(es[col[i]] + edv, 0.2f);
        int k = i - s;
        if (k < 32) lg[k] = t;
        m = fmaxf(m, t);
    }
    float wsl = __expf(eself - m);
    float den = wsl;
    for (i = s; i < e; i++) {
        int k = i - s;
        float t = (k < 32) ? lg[k] : lrelu(es[col[i]] + edv, 0.2f);
        float w = __expf(t - m);
        if (k < 32) lg[k] = w;
        den += w;
    }
    float inv = 1.f / den;
    for (i = s; i < e; i++) {
        int k = i - s;
        float w = (k < 32) ? lg[k] : __expf(lrelu(es[col[i]] + edv, 0.2f) - m);
        ewi[i] = (f16)(w * inv);
    }
    wsi[v] = wsl * inv;
}

// ---------------- edge-parallel GAT aggregation + piece-mean pooling ----------------
__global__ __launch_bounds__(256) void gat_agg_pool_k(const f16* __restrict__ y, const int* __restrict__ rp,
                                                      const int* __restrict__ col, const f16* __restrict__ ewi,
                                                      const float* __restrict__ wsi,
                                                      const float* __restrict__ bias, float* __restrict__ pooled) {
    __shared__ float sred[32 * 68];
    const int g = blockIdx.x;
    const int tid = threadIdx.x;
    const int idx = tid & 7;
    const int slot = tid >> 3;
    const f16x8* y8 = (const f16x8*)y;
    float acc[8];
#pragma unroll
    for (int j = 0; j < 8; j++) acc[j] = 0.f;

#pragma unroll
    for (int pass = 0; pass < 4; pass++) {
        const int v = g * 128 + pass * 32 + slot;
        float ws = wsi[v];
        f16x8 self = y8[(size_t)v * 8 + idx];
#pragma unroll
        for (int j = 0; j < 8; j++) acc[j] = fmaf(ws, (float)self[j], acc[j]);
    }

    const int s = rp[g * 128];
    const int e = rp[g * 128 + 128];
    int i = s + slot;
    for (; i + 96 < e; i += 128) {
        int u0 = col[i], u1 = col[i + 32], u2 = col[i + 64], u3 = col[i + 96];
        float w0 = (float)ewi[i], w1 = (float)ewi[i + 32], w2 = (float)ewi[i + 64], w3 = (float)ewi[i + 96];
        f16x8 a0 = y8[(size_t)u0 * 8 + idx];
        f16x8 a1 = y8[(size_t)u1 * 8 + idx];
        f16x8 a2 = y8[(size_t)u2 * 8 + idx];
        f16x8 a3 = y8[(size_t)u3 * 8 + idx];
#pragma unroll
        for (int j = 0; j < 8; j++)
            acc[j] = fmaf(w0, (float)a0[j], fmaf(w1, (float)a1[j], fmaf(w2, (float)a2[j], fmaf(w3, (float)a3[j], acc[j]))));
    }
    for (; i < e; i += 32) {
        int u = col[i];
        float w = (float)ewi[i];
        f16x8 a = y8[(size_t)u * 8 + idx];
#pragma unroll
        for (int j = 0; j < 8; j++) acc[j] = fmaf(w, (float)a[j], acc[j]);
    }

#pragma unroll
    for (int j = 0; j < 8; j++) sred[slot * 68 + idx * 8 + j] = acc[j];
    __syncthreads();
    if (tid < 64) {
        float s2 = 0.f;
#pragma unroll
        for (int k = 0; k < 32; k++) s2 += sred[k * 68 + tid];
        pooled[(size_t)g * 64 + tid] = s2 * (1.f / 128.f) + bias[tid];
    }
}

// ---------------- pooling (cross) ----------------
__global__ void pool_cross_k(const float* __restrict__ in, float* __restrict__ out) {
    int gid = blockIdx.x * 64 + threadIdx.x;
    if (gid >= BB * 64) return;
    int f = gid & 63, b = gid >> 6;
    const float* p = in + (size_t)b * CCROSS * 64 + f;
    float s = 0.f;
#pragma unroll
    for (int i = 0; i < CCROSS; i++) s += p[(size_t)i * 64];
    out[gid] = s * (1.f / 32.f);
}

// ---------------- GAT input gemm (fp32, small cross-graph path) ----------------
template <int KIN, int KOUT>
__global__ void gat_gemm_k(const float* __restrict__ x, const float* __restrict__ W,
                           float* __restrict__ y, const float* __restrict__ av, const float* __restrict__ ad,
                           float* __restrict__ es, float* __restrict__ ed, int n) {
    int v = blockIdx.x * 256 + threadIdx.x;
    if (v >= n) return;
    const float* xr = x + (size_t)v * KIN;
    float acc[KOUT];
#pragma unroll
    for (int j = 0; j < KOUT; j++) acc[j] = 0.f;
#pragma unroll 2
    for (int k = 0; k < KIN; k++) {
        float xv = xr[k];
#pragma unroll
        for (int j = 0; j < KOUT; j++) acc[j] = fmaf(xv, W[k * KOUT + j], acc[j]);
    }
    float e1 = 0.f, e2 = 0.f;
    float4* y4 = (float4*)(y + (size_t)v * KOUT);
#pragma unroll
    for (int j4 = 0; j4 < KOUT / 4; j4++) {
        float4 t;
        t.x = acc[4 * j4 + 0]; t.y = acc[4 * j4 + 1]; t.z = acc[4 * j4 + 2]; t.w = acc[4 * j4 + 3];
        y4[j4] = t;
        e1 = fmaf(t.x, av[4 * j4 + 0], e1); e1 = fmaf(t.y, av[4 * j4 + 1], e1);
        e1 = fmaf(t.z, av[4 * j4 + 2], e1); e1 = fmaf(t.w, av[4 * j4 + 3], e1);
        e2 = fmaf(t.x, ad[4 * j4 + 0], e2); e2 = fmaf(t.y, ad[4 * j4 + 1], e2);
        e2 = fmaf(t.z, ad[4 * j4 + 2], e2); e2 = fmaf(t.w, ad[4 * j4 + 3], e2);
    }
    es[v] = e1; ed[v] = e2;
}

// ---------------- dense cross-graph GAT ----------------
__global__ void cross_att_k(const float* __restrict__ xw, const float* __restrict__ es,
                            const float* __restrict__ ed, const float* __restrict__ bg,
                            float* __restrict__ out) {
    int gid = blockIdx.x * 256 + threadIdx.x;
    if (gid >= BB * CCROSS * 64) return;
    int f = gid & 63;
    int d = (gid >> 6) & 31;
    int g = gid >> 11;
    int base = g * CCROSS;
    float edd = ed[base + d];
    float m = -1e30f;
#pragma unroll
    for (int s = 0; s < CCROSS; s++) {
        float e = lrelu(es[base + s] + edd, 0.2f);
        m = fmaxf(m, e);
    }
    float den = 0.f, acc = 0.f;
#pragma unroll
    for (int s = 0; s < CCROSS; s++) {
        float e = lrelu(es[base + s] + edd, 0.2f);
        float w = __expf(e - m) * ((s == d) ? 1.f : 2.f);
        den += w;
        acc = fmaf(w, xw[(size_t)(base + s) * 64 + f], acc);
    }
    out[gid] = acc / den + bg[f];
}

// ---------------- fused conv branch (transposed f16 stages + dot2, 512 blocks) ----------------
__global__ __launch_bounds__(256) void conv_fused_k(
        const float* __restrict__ pts, const float* __restrict__ c1W, const float* __restrict__ c1b,
        const float* __restrict__ g1, const float* __restrict__ be1,
        const f16* __restrict__ w2p, const float* __restrict__ c2b,
        const float* __restrict__ g2, const float* __restrict__ be2,
        const f16* __restrict__ w3pc, const float* __restrict__ c3b,
        float* __restrict__ partials) {
    __shared__ __align__(16) float s0[3 * 264];
    __shared__ __align__(16) f16 s1T[132 * 32];
    __shared__ __align__(16) f16 s2T[66 * 64];
    __shared__ float sred[256];

    const int b = blockIdx.x >> 3;
    const int q = blockIdx.x & 7;
    const int tid = threadIdx.x;
    const float bnscale = 0.99999500003749968f;

    const int lo0 = 256 * q - 7;
    for (int t = tid; t < 3 * 263; t += 256) {
        int c = t / 263, j = t - c * 263;
        int p = lo0 + j;
        s0[c * 264 + j] = (p >= 0 && p < PP) ? pts[((size_t)b * 3 + c) * PP + p] : 0.f;
    }
    __syncthreads();

    {
        const int ch = tid & 31;
        const int j0 = tid >> 5;
        float wv[9];
        const float* wg = c1W + ch * 9;
#pragma unroll
        for (int t = 0; t < 9; t++) wv[t] = wg[t];
        const float bs = c1b[ch];
        const float gs = g1[ch] * bnscale;
        const float bt = be1[ch];
        const int lo1 = 128 * q - 3;
        for (int j = j0; j < 131; j += 8) {
            int p1 = lo1 + j;
            float v = 0.f;
            if (p1 >= 0 && p1 < 1024) {
                const float* x0 = s0 + 2 * j;
                float a0 = bs, a1 = 0.f, a2 = 0.f;
#pragma unroll
                for (int c = 0; c < 3; c++) {
                    float2 x01 = *(const float2*)(x0 + c * 264);
                    float x2v = x0[c * 264 + 2];
                    a0 = fmaf(x01.x, wv[c * 3 + 0], a0);
                    a1 = fmaf(x01.y, wv[c * 3 + 1], a1);
                    a2 = fmaf(x2v, wv[c * 3 + 2], a2);
                }
                float acc = a0 + a1 + a2;
                acc = lrelu(acc, 0.01f);
                v = fmaf(acc, gs, bt);
            }
            s1T[j * 32 + ch] = (f16)v;
        }
    }
    __syncthreads();

    {
        const int ch = tid & 63;
        const int jg = tid >> 6;
        unsigned wr[48];
        const uint4* wp = (const uint4*)(w2p + (size_t)ch * 96);
#pragma unroll
        for (int t = 0; t < 12; t++) {
            uint4 u = wp[t];
            wr[4 * t + 0] = u.x; wr[4 * t + 1] = u.y; wr[4 * t + 2] = u.z; wr[4 * t + 3] = u.w;
        }
        const float bs = c2b[ch];
        const float gs = g2[ch] * bnscale;
        const float bt = be2[ch];
        const int lo2v = 64 * q - 1;
        for (int j = jg; j < 65; j += 4) {
            float ak[3] = {bs, 0.f, 0.f};
#pragma unroll
            for (int k = 0; k < 3; k++) {
                const uint4* xp = (const uint4*)(s1T + (2 * j + k) * 32);
                uint4 x0 = xp[0], x1 = xp[1], x2 = xp[2], x3 = xp[3];
                float a = ak[k];
                a = dot2f(x0.x, wr[k * 16 + 0], a);
                a = dot2f(x0.y, wr[k * 16 + 1], a);
                a = dot2f(x0.z, wr[k * 16 + 2], a);
                a = dot2f(x0.w, wr[k * 16 + 3], a);
                a = dot2f(x1.x, wr[k * 16 + 4], a);
                a = dot2f(x1.y, wr[k * 16 + 5], a);
                a = dot2f(x1.z, wr[k * 16 + 6], a);
                a = dot2f(x1.w, wr[k * 16 + 7], a);
                a = dot2f(x2.x, wr[k * 16 + 8], a);
                a = dot2f(x2.y, wr[k * 16 + 9], a);
                a = dot2f(x2.z, wr[k * 16 + 10], a);
                a = dot2f(x2.w, wr[k * 16 + 11], a);
                a = dot2f(x3.x, wr[k * 16 + 12], a);
                a = dot2f(x3.y, wr[k * 16 + 13], a);
                a = dot2f(x3.z, wr[k * 16 + 14], a);
                a = dot2f(x3.w, wr[k * 16 + 15], a);
                ak[k] = a;
            }
            float acc = ak[0] + ak[1] + ak[2];
            int p2 = lo2v + j;
            float v = 0.f;
            if (p2 >= 0 && p2 < 512) v = fmaf(lrelu(acc, 0.01f), gs, bt);
            s2T[j * 64 + ch] = (f16)v;
        }
    }
    __syncthreads();

    {
        const int ch = tid & 63;
        const int jg = tid >> 6;
        unsigned wr[96];
        const uint4* wp = (const uint4*)(w3pc + (size_t)ch * 192);
#pragma unroll
        for (int t = 0; t < 24; t++) {
            uint4 u = wp[t];
            wr[4 * t + 0] = u.x; wr[4 * t + 1] = u.y; wr[4 * t + 2] = u.z; wr[4 * t + 3] = u.w;
        }
        const float bs = c3b[ch];
        float psum = 0.f;
        for (int j = jg; j < 32; j += 4) {
            float ak[3] = {bs, 0.f, 0.f};
#pragma unroll
            for (int k = 0; k < 3; k++) {
                const uint4* xp = (const uint4*)(s2T + (2 * j + k) * 64);
                float a = ak[k];
#pragma unroll
                for (int t = 0; t < 8; t++) {
                    uint4 xv = xp[t];
                    a = dot2f(xv.x, wr[k * 32 + 4 * t + 0], a);
                    a = dot2f(xv.y, wr[k * 32 + 4 * t + 1], a);
                    a = dot2f(xv.z, wr[k * 32 + 4 * t + 2], a);
                    a = dot2f(xv.w, wr[k * 32 + 4 * t + 3], a);
                }
                ak[k] = a;
            }
            psum += lrelu(ak[0] + ak[1] + ak[2], 0.01f);
        }
        sred[tid] = psum;
    }
    __syncthreads();
    if (tid < 64) {
        float s = sred[tid] + sred[tid + 64] + sred[tid + 128] + sred[tid + 192];
        partials[((size_t)b * 8 + q) * 64 + tid] = s;
    }
}

// ---------------- head ----------------
__global__ void head_k(const float* __restrict__ hG, const float* __restrict__ partials,
                       const float* __restrict__ Wl2, const float* __restrict__ bl2,
                       const float* __restrict__ Wl3, const float* __restrict__ bl3,
                       float* __restrict__ out) {
    int b = blockIdx.x;
    int f = threadIdx.x;  // 64
    __shared__ float sh[64];
    float p = 0.f;
#pragma unroll
    for (int q = 0; q < 8; q++) p += partials[((size_t)b * 8 + q) * 64 + f];
    float h = hG[b * 64 + f] + p * (1.f / 256.f);
    sh[f] = h;
    __syncthreads();
    float acc = bl2[f];
#pragma unroll
    for (int k = 0; k < 64; k++) acc = fmaf(sh[k], Wl2[k * 64 + f], acc);
    acc = lrelu(acc, 0.01f);
    float pr = acc * Wl3[f];
#pragma unroll
    for (int off = 32; off > 0; off >>= 1) pr += __shfl_down(pr, off, 64);
    if (f == 0) out[b] = 1.f / (1.f + __expf(-(pr + bl3[0])));
}

extern "C" void kernel_launch(void* const* d_in, const int* in_sizes, int n_in,
                              void* d_out, int out_size, void* d_ws, size_t ws_size,
                              hipStream_t stream) {
    const float* x = (const float*)d_in[0];
    const int* ei = (const int*)d_in[1];
    const float* points = (const float*)d_in[2];
    const float* W1 = (const float*)d_in[3];
    const float* b1 = (const float*)d_in[4];
    const float* W2 = (const float*)d_in[5];
    const float* b2 = (const float*)d_in[6];
    const float* W3 = (const float*)d_in[7];
    const float* b3 = (const float*)d_in[8];
    const float* Wg1 = (const float*)d_in[9];
    const float* asrc1 = (const float*)d_in[10];
    const float* adst1 = (const float*)d_in[11];
    const float* bg1 = (const float*)d_in[12];
    const float* Wg2 = (const float*)d_in[13];
    const float* asrc2 = (const float*)d_in[14];
    const float* adst2 = (const float*)d_in[15];
    const float* bg2 = (const float*)d_in[16];
    const float* c1W = (const float*)d_in[17];
    const float* c1b = (const float*)d_in[18];
    const float* g1 = (const float*)d_in[19];
    const float* be1 = (const float*)d_in[20];
    const float* c2W = (const float*)d_in[21];
    const float* c2b = (const float*)d_in[22];
    const float* g2 = (const float*)d_in[23];
    const float* be2 = (const float*)d_in[24];
    const float* c3W = (const float*)d_in[25];
    const float* c3b = (const float*)d_in[26];
    const float* Wl2 = (const float*)d_in[27];
    const float* bl2 = (const float*)d_in[28];
    const float* Wl3 = (const float*)d_in[29];
    const float* bl3 = (const float*)d_in[30];

    const int* src = ei;
    const int* dst = ei + EE;

    // ---- workspace carve-up ----
    char* w = (char*)d_ws;
    size_t off = 0;
    auto A = [&](size_t bytes) -> void* {
        void* p = w + off;
        off = (off + bytes + 255) & ~(size_t)255;
        return p;
    };
    int* colb = (int*)A((size_t)EE * 4);
    int* rp = (int*)A((size_t)(NN + 1) * 4);
    int* gcnt = (int*)A(NBUCK * 4);
    int* bbase = (int*)A(NBUCK * 4);
    float* dinv = (float*)A((size_t)NN * 4);
    float* bufA = (float*)A((size_t)NN * 64 * 4);
    f16* bufH1 = (f16*)A((size_t)NN * 64 * 2);
    f16* bufH2 = (f16*)A((size_t)NN * 64 * 2);
    f16* ewi = (f16*)A((size_t)EE * 2);
    float* wsi = (float*)A((size_t)NN * 4);
    float* es = (float*)A((size_t)NN * 4);
    float* edv = (float*)A((size_t)NN * 4);
    f16* w3p = (f16*)A(4096 * 2);
    f16* wgp = (f16*)A(4096 * 2);
    f16* wc2p = (f16*)A(64 * 96 * 2);
    f16* wc3p = (f16*)A(64 * 192 * 2);
    float* pooled = (float*)A((size_t)BB * CCROSS * 64 * 4);
    float* xw2 = (float*)A((size_t)BB * CCROSS * 64 * 4);
    float* es2 = (float*)A((size_t)BB * CCROSS * 4);
    float* ed2 = (float*)A((size_t)BB * CCROSS * 4);
    float* crosso = (float*)A((size_t)BB * CCROSS * 64 * 4);
    float* hG = (float*)A((size_t)BB * 64 * 4);
    float* partials = (float*)A((size_t)BB * 8 * 64 * 4);

    unsigned* buckets = (unsigned*)bufA;   // aliases bufA; dead after CSR build

    // ---- CSR build (bucketed) ----
    hipMemsetAsync(gcnt, 0, NBUCK * 4, stream);
    bucket_a_k<<<EE / 8192, 256, 0, stream>>>(src, dst, buckets, gcnt);
    bucket_scan_k<<<1, 256, 0, stream>>>(gcnt, bbase, rp);
    bucket_b_k<<<NBUCK, 256, 0, stream>>>(buckets, gcnt, bbase, rp, dinv, colb);

    // ---- points branch + weight packing ----
    pack_c2_k<<<24, 256, 0, stream>>>(c2W, wc2p);
    pack_c3_k<<<48, 256, 0, stream>>>(c3W, wc3p);
    conv_fused_k<<<BB * 8, 256, 0, stream>>>(points, c1W, c1b, g1, be1, wc2p, c2b, g2, be2, wc3p, c3b, partials);
    pack_w_k<<<16, 256, 0, stream>>>(W3, w3p);
    pack_w_k<<<16, 256, 0, stream>>>(Wg1, wgp);

    // ---- GCN 1/2 (fused agg+gemm), GCN3+GAT gemm (edge-parallel gather fused into MFMA kernel) ----
    zprep_k<<<NN / 256, 256, 0, stream>>>(x, dinv, bufH1);                               // H1 = z1 [NN x 32h]
    fused_agg_gemm_k<19, 32, 0><<<NN / 64, 256, 0, stream>>>(bufH1, rp, colb, W1, dinv, b1, bufH2);  // H2 = z2
    fused_agg_gemm_k<32, 64, 1><<<NN / 64, 256, 0, stream>>>(bufH2, rp, colb, W2, dinv, b2, bufH1);  // H1 = z3
    gemm3_gat_k<<<NN / 64, 256, 0, stream>>>(bufH1, rp, colb, w3p, dinv, b3, wgp, asrc1, adst1,
                                             bufH2, es, edv);                            // H2 = xw, es/ed

    // ---- GAT 1 softmax (normalization folded) + edge-parallel aggregation+pooling ----
    gat_w_k<<<NN / 256, 256, 0, stream>>>(es, edv, rp, colb, ewi, wsi);
    gat_agg_pool_k<<<BB * CCROSS, 256, 0, stream>>>(bufH2, rp, colb, ewi, wsi, bg1, pooled);

    // ---- cross GAT -> pool cross ----
    gat_gemm_k<64, 64><<<(BB * CCROSS) / 256, 256, 0, stream>>>(pooled, Wg2, xw2, asrc2, adst2, es2, ed2, BB * CCROSS);
    cross_att_k<<<(BB * CCROSS * 64) / 256, 256, 0, stream>>>(xw2, es2, ed2, bg2, crosso);
    pool_cross_k<<<BB, 64, 0, stream>>>(crosso, hG);

    // ---- head ----
    head_k<<<BB, 64, 0, stream>>>(hG, partials, Wl2, bl2, Wl3, bl3, (float*)d_out);
}

// Round 6
// 480.447 us; speedup vs baseline: 1.1909x; 1.1909x over previous
//
#include <hip/hip_runtime.h>
#include <cstdint>
#include <cstddef>

#define NN 262144
#define EE 2097152
#define BB 64
#define CCROSS 32
#define PCC 128
#define PP 2048
#define NBUCK 256
#define BCAP 12288

typedef _Float16 f16;
typedef __attribute__((ext_vector_type(2))) _Float16 f16x2;
typedef __attribute__((ext_vector_type(4))) _Float16 f16x4;
typedef __attribute__((ext_vector_type(8))) _Float16 f16x8;
typedef __attribute__((ext_vector_type(4))) float f32x4;

static __device__ __forceinline__ float lrelu(float x, float s) { return x > 0.f ? x : s * x; }

#if __has_builtin(__builtin_amdgcn_fdot2)
static __device__ __forceinline__ float dot2f(unsigned x, unsigned w, float c) {
    return __builtin_amdgcn_fdot2(__builtin_bit_cast(f16x2, x), __builtin_bit_cast(f16x2, w), c, false);
}
#else
static __device__ __forceinline__ float dot2f(unsigned x, unsigned w, float c) {
    f16x2 a = __builtin_bit_cast(f16x2, x);
    f16x2 b = __builtin_bit_cast(f16x2, w);
    return fmaf((float)a[0], (float)b[0], fmaf((float)a[1], (float)b[1], c));
}
#endif

// ---------------- bucketed CSR build ----------------
__global__ __launch_bounds__(256) void bucket_a_k(const int* __restrict__ src, const int* __restrict__ dst,
                                                  unsigned* __restrict__ buckets, int* __restrict__ gcnt) {
    __shared__ int hist[NBUCK];
    __shared__ int base[NBUCK];
    __shared__ unsigned short rankbuf[8192];
    const int tid = threadIdx.x;
    const int e0 = blockIdx.x * 8192;
    hist[tid] = 0;
    __syncthreads();
    for (int i = tid; i < 8192; i += 256) {
        int d = dst[e0 + i];
        rankbuf[i] = (unsigned short)atomicAdd(&hist[d >> 10], 1);
    }
    __syncthreads();
    base[tid] = tid * BCAP + atomicAdd(&gcnt[tid], hist[tid]);
    __syncthreads();
    for (int i = tid; i < 8192; i += 256) {
        int s = src[e0 + i];
        int d = dst[e0 + i];
        int b = d >> 10;
        buckets[base[b] + rankbuf[i]] = ((unsigned)s << 10) | (unsigned)(d & 1023);
    }
}

__global__ void bucket_scan_k(const int* __restrict__ gcnt, int* __restrict__ bbase, int* __restrict__ rp) {
    __shared__ int tmp[256];
    int tid = threadIdx.x;
    int v = gcnt[tid];
    tmp[tid] = v;
    __syncthreads();
    for (int off = 1; off < 256; off <<= 1) {
        int t = (tid >= off) ? tmp[tid - off] : 0;
        __syncthreads();
        tmp[tid] += t;
        __syncthreads();
    }
    bbase[tid] = tmp[tid] - v;
    if (tid == 0) rp[NN] = EE;
}

__global__ __launch_bounds__(256) void bucket_b_k(const unsigned* __restrict__ buckets, const int* __restrict__ gcnt,
                                                  const int* __restrict__ bbase, int* __restrict__ rp,
                                                  float* __restrict__ dinv, int* __restrict__ col) {
    __shared__ int cnt[1024];
    __shared__ int scan[1024];
    __shared__ int wsum[256];
    const int b = blockIdx.x;
    const int tid = threadIdx.x;
    int n = gcnt[b];
    if (n > BCAP) n = BCAP;
    const unsigned* eb = buckets + (size_t)b * BCAP;
    const int gb = bbase[b];
    for (int i = tid; i < 1024; i += 256) cnt[i] = 0;
    __syncthreads();
    for (int i = tid; i < n; i += 256) atomicAdd(&cnt[eb[i] & 1023], 1);
    __syncthreads();
    int b4 = tid * 4;
    int c0 = cnt[b4], c1 = cnt[b4 + 1], c2 = cnt[b4 + 2], c3 = cnt[b4 + 3];
    int tsum = c0 + c1 + c2 + c3;
    wsum[tid] = tsum;
    __syncthreads();
    for (int off = 1; off < 256; off <<= 1) {
        int t = (tid >= off) ? wsum[tid - off] : 0;
        __syncthreads();
        wsum[tid] += t;
        __syncthreads();
    }
    int excl = wsum[tid] - tsum;
    scan[b4] = excl;
    scan[b4 + 1] = excl + c0;
    scan[b4 + 2] = excl + c0 + c1;
    scan[b4 + 3] = excl + c0 + c1 + c2;
    int vbase = b * 1024 + b4;
    rp[vbase + 0] = gb + scan[b4 + 0];
    rp[vbase + 1] = gb + scan[b4 + 1];
    rp[vbase + 2] = gb + scan[b4 + 2];
    rp[vbase + 3] = gb + scan[b4 + 3];
    dinv[vbase + 0] = rsqrtf((float)(c0 + 1));
    dinv[vbase + 1] = rsqrtf((float)(c1 + 1));
    dinv[vbase + 2] = rsqrtf((float)(c2 + 1));
    dinv[vbase + 3] = rsqrtf((float)(c3 + 1));
    __syncthreads();
    for (int i = tid; i < 1024; i += 256) cnt[i] = 0;
    __syncthreads();
    for (int i = tid; i < n; i += 256) {
        unsigned p = eb[i];
        int dl = p & 1023;
        int r = atomicAdd(&cnt[dl], 1);
        col[gb + scan[dl] + r] = (int)(p >> 10);
    }
}

// ---------------- z-prep ----------------
__global__ void zprep_k(const float* __restrict__ x, const float* __restrict__ dinv, f16* __restrict__ z) {
    int v = blockIdx.x * 256 + threadIdx.x;
    if (v >= NN) return;
    float dv = dinv[v];
    const float* xr = x + (size_t)v * 19;
    float vv[20];
#pragma unroll
    for (int k = 0; k < 19; k++) vv[k] = dv * xr[k];
    vv[19] = 0.f;
    f16x4* zr = (f16x4*)(z + (size_t)v * 32);
#pragma unroll
    for (int c = 0; c < 5; c++) {
        f16x4 t = {(f16)vv[4 * c], (f16)vv[4 * c + 1], (f16)vv[4 * c + 2], (f16)vv[4 * c + 3]};
        zr[c] = t;
    }
    f16x4 zz = {(f16)0.f, (f16)0.f, (f16)0.f, (f16)0.f};
#pragma unroll
    for (int c = 5; c < 8; c++) zr[c] = zz;
}

// ---------------- fused agg (64B fp16 rows) + gemm, wide-gather version ----------------
#define ZSTR1 36
template <int KINR, int KOUT, int ACT>
__global__ __launch_bounds__(256) void fused_agg_gemm_k(const f16* __restrict__ z, const int* __restrict__ rp,
                                                        const int* __restrict__ col, const float* __restrict__ Wg,
                                                        const float* __restrict__ dinv, const float* __restrict__ bias,
                                                        f16* __restrict__ zout) {
    constexpr int NO = KOUT / 4;
    __shared__ float Wl[32 * KOUT];
    __shared__ float zrow[64 * ZSTR1];
    const int tid = threadIdx.x;
    for (int i = tid; i < 32 * KOUT; i += 256) Wl[i] = (i < KINR * KOUT) ? Wg[i] : 0.f;

    const int r = tid >> 2;
    const int idx = tid & 3;
    const int v = blockIdx.x * 64 + r;
    const f16x8* z8 = (const f16x8*)z;
    f16x8 a = z8[(size_t)v * 4 + idx];
    float acc8[8];
#pragma unroll
    for (int j = 0; j < 8; j++) acc8[j] = (float)a[j];
    int st = rp[v], e = rp[v + 1];
    int i = st;
    for (; i + 4 <= e; i += 4) {
        int u0 = col[i], u1 = col[i + 1], u2 = col[i + 2], u3 = col[i + 3];
        f16x8 a0 = z8[(size_t)u0 * 4 + idx];
        f16x8 a1 = z8[(size_t)u1 * 4 + idx];
        f16x8 a2 = z8[(size_t)u2 * 4 + idx];
        f16x8 a3 = z8[(size_t)u3 * 4 + idx];
#pragma unroll
        for (int j = 0; j < 8; j++)
            acc8[j] += ((float)a0[j] + (float)a1[j]) + ((float)a2[j] + (float)a3[j]);
    }
    for (; i < e; i++) {
        f16x8 aa = z8[(size_t)col[i] * 4 + idx];
#pragma unroll
        for (int j = 0; j < 8; j++) acc8[j] += (float)aa[j];
    }
    float4 s0, s1;
    s0.x = acc8[0]; s0.y = acc8[1]; s0.z = acc8[2]; s0.w = acc8[3];
    s1.x = acc8[4]; s1.y = acc8[5]; s1.z = acc8[6]; s1.w = acc8[7];
    *(float4*)&zrow[r * ZSTR1 + idx * 8] = s0;
    *(float4*)&zrow[r * ZSTR1 + idx * 8 + 4] = s1;
    __syncthreads();

    float acc[NO];
#pragma unroll
    for (int j = 0; j < NO; j++) acc[j] = 0.f;
#pragma unroll 4
    for (int k = 0; k < 32; k++) {
        float zv = zrow[r * ZSTR1 + k];
        const float* wr = Wl + k * KOUT + NO * idx;
#pragma unroll
        for (int j = 0; j < NO; j++) acc[j] = fmaf(zv, wr[j], acc[j]);
    }
    float dv = dinv[v];
    f16 hv[NO];
#pragma unroll
    for (int j = 0; j < NO; j++) {
        float o = dv * acc[j] + bias[NO * idx + j];
        o = (ACT == 0) ? fmaxf(o, 0.f) : lrelu(o, 0.01f);
        hv[j] = (f16)(o * dv);
    }
    if constexpr (NO == 8) {
        f16x8 h = {hv[0], hv[1], hv[2], hv[3], hv[4], hv[5], hv[6], hv[7]};
        *(f16x8*)(zout + (size_t)v * KOUT + NO * idx) = h;
    } else {
        f16x8 h0 = {hv[0], hv[1], hv[2], hv[3], hv[4], hv[5], hv[6], hv[7]};
        f16x8 h1 = {hv[8], hv[9], hv[10], hv[11], hv[12], hv[13], hv[14], hv[15]};
        f16x8* yo = (f16x8*)(zout + (size_t)v * KOUT + NO * idx);
        yo[0] = h0; yo[1] = h1;
    }
}

// ---------------- pack W (64x64 fp32 row-major k x n) into fp16 B-fragment order ----------------
__global__ void pack_w_k(const float* __restrict__ W, f16* __restrict__ out) {
    int o = blockIdx.x * 256 + threadIdx.x;
    if (o >= 4096) return;
    int frag = o >> 9;
    int kt = frag >> 2;
    int c = frag & 3;
    int idx = o & 511;
    int l = idx >> 3;
    int j = idx & 7;
    int k = kt * 32 + ((l >> 4) << 3) + j;
    int n = 16 * c + (l & 15);
    out[o] = (f16)W[k * 64 + n];
}

// ---------------- pack conv weights to f16, k-major (pairs along in-ch for dot2) ----------------
__global__ void pack_c2_k(const float* __restrict__ W, f16* __restrict__ out) {
    int o = blockIdx.x * 256 + threadIdx.x;  // 64*96
    if (o >= 64 * 96) return;
    int ch = o / 96, r = o - ch * 96;
    int k = r >> 5, ci = r & 31;
    out[o] = (f16)W[ch * 96 + ci * 3 + k];
}

__global__ void pack_c3_k(const float* __restrict__ W, f16* __restrict__ out) {
    int o = blockIdx.x * 256 + threadIdx.x;  // 64*192
    if (o >= 64 * 192) return;
    int ch = o / 192, r = o - ch * 192;
    int k = r >> 6, ci = r & 63;
    out[o] = (f16)W[ch * 192 + ci * 3 + k];
}

// ---------------- fused: agg(z3) gather -> LDS; h3 = lrelu(dinv*(agg@W3)+b3); xw = h3@Wg1; es/ed ----------------
// Gather phase: 4 lanes/row x 64 rows; each lane accumulates 16 features (2x f16x8 loads per neighbor),
// neighbor loop unrolled x4 (8 independent 16B loads in flight per lane).
#define HSTR 72
__global__ __launch_bounds__(256) void gemm3_gat_k(const f16* __restrict__ y, const int* __restrict__ rp,
                                                   const int* __restrict__ col, const f16* __restrict__ w3p,
                                                   const float* __restrict__ dinv, const float* __restrict__ b3,
                                                   const f16* __restrict__ wgp, const float* __restrict__ av,
                                                   const float* __restrict__ ad, f16* __restrict__ xw,
                                                   float* __restrict__ es, float* __restrict__ ed) {
    __shared__ f16 zin[64 * HSTR];
    __shared__ f16 hh[64 * HSTR];
    const int tid = threadIdx.x;
    const int v0 = blockIdx.x * 64;
    {
        const int row = tid >> 2;
        const int idx = tid & 3;  // 32B chunk idx: features idx*16 .. idx*16+15
        const int v = v0 + row;
        const f16x8* y8 = (const f16x8*)y;
        f16x8 s0 = y8[(size_t)v * 8 + idx * 2];
        f16x8 s1 = y8[(size_t)v * 8 + idx * 2 + 1];
        float acc[16];
#pragma unroll
        for (int j = 0; j < 8; j++) { acc[j] = (float)s0[j]; acc[8 + j] = (float)s1[j]; }
        int s = rp[v], e = rp[v + 1];
        int i = s;
        for (; i + 4 <= e; i += 4) {
            int u0 = col[i], u1 = col[i + 1], u2 = col[i + 2], u3 = col[i + 3];
            f16x8 a0 = y8[(size_t)u0 * 8 + idx * 2];
            f16x8 a1 = y8[(size_t)u0 * 8 + idx * 2 + 1];
            f16x8 b0 = y8[(size_t)u1 * 8 + idx * 2];
            f16x8 b1 = y8[(size_t)u1 * 8 + idx * 2 + 1];
            f16x8 c0 = y8[(size_t)u2 * 8 + idx * 2];
            f16x8 c1 = y8[(size_t)u2 * 8 + idx * 2 + 1];
            f16x8 d0 = y8[(size_t)u3 * 8 + idx * 2];
            f16x8 d1 = y8[(size_t)u3 * 8 + idx * 2 + 1];
#pragma unroll
            for (int j = 0; j < 8; j++) {
                acc[j] += ((float)a0[j] + (float)b0[j]) + ((float)c0[j] + (float)d0[j]);
                acc[8 + j] += ((float)a1[j] + (float)b1[j]) + ((float)c1[j] + (float)d1[j]);
            }
        }
        for (; i < e; i++) {
            int u = col[i];
            f16x8 a0 = y8[(size_t)u * 8 + idx * 2];
            f16x8 a1 = y8[(size_t)u * 8 + idx * 2 + 1];
#pragma unroll
            for (int j = 0; j < 8; j++) { acc[j] += (float)a0[j]; acc[8 + j] += (float)a1[j]; }
        }
        f16x8 o0, o1;
#pragma unroll
        for (int j = 0; j < 8; j++) { o0[j] = (f16)acc[j]; o1[j] = (f16)acc[8 + j]; }
        *(f16x8*)&zin[row * HSTR + idx * 16] = o0;
        *(f16x8*)&zin[row * HSTR + idx * 16 + 8] = o1;
    }
    __syncthreads();

    const int w = tid >> 6;
    const int l = tid & 63;
    const int m = l & 15;
    const int q = l >> 4;
    const int r0 = 16 * w;

    f32x4 acc0 = {0.f, 0.f, 0.f, 0.f}, acc1 = acc0, acc2 = acc0, acc3 = acc0;
#pragma unroll
    for (int kt = 0; kt < 2; kt++) {
        f16x8 afrag = *(const f16x8*)&zin[(r0 + m) * HSTR + kt * 32 + q * 8];
        f16x8 b0 = *(const f16x8*)&w3p[((kt * 4 + 0) << 9) + l * 8];
        f16x8 b1 = *(const f16x8*)&w3p[((kt * 4 + 1) << 9) + l * 8];
        f16x8 b2 = *(const f16x8*)&w3p[((kt * 4 + 2) << 9) + l * 8];
        f16x8 b3f = *(const f16x8*)&w3p[((kt * 4 + 3) << 9) + l * 8];
        acc0 = __builtin_amdgcn_mfma_f32_16x16x32_f16(afrag, b0, acc0, 0, 0, 0);
        acc1 = __builtin_amdgcn_mfma_f32_16x16x32_f16(afrag, b1, acc1, 0, 0, 0);
        acc2 = __builtin_amdgcn_mfma_f32_16x16x32_f16(afrag, b2, acc2, 0, 0, 0);
        acc3 = __builtin_amdgcn_mfma_f32_16x16x32_f16(afrag, b3f, acc3, 0, 0, 0);
    }
    {
        float dv0 = dinv[v0 + r0 + q * 4 + 0];
        float dv1 = dinv[v0 + r0 + q * 4 + 1];
        float dv2 = dinv[v0 + r0 + q * 4 + 2];
        float dv3 = dinv[v0 + r0 + q * 4 + 3];
#pragma unroll
        for (int c = 0; c < 4; c++) {
            const f32x4* ac = (c == 0) ? &acc0 : (c == 1) ? &acc1 : (c == 2) ? &acc2 : &acc3;
            float bb = b3[16 * c + m];
            hh[(r0 + q * 4 + 0) * HSTR + 16 * c + m] = (f16)lrelu(dv0 * (*ac)[0] + bb, 0.01f);
            hh[(r0 + q * 4 + 1) * HSTR + 16 * c + m] = (f16)lrelu(dv1 * (*ac)[1] + bb, 0.01f);
            hh[(r0 + q * 4 + 2) * HSTR + 16 * c + m] = (f16)lrelu(dv2 * (*ac)[2] + bb, 0.01f);
            hh[(r0 + q * 4 + 3) * HSTR + 16 * c + m] = (f16)lrelu(dv3 * (*ac)[3] + bb, 0.01f);
        }
    }
    __syncthreads();

    acc0 = (f32x4){0.f, 0.f, 0.f, 0.f}; acc1 = acc0; acc2 = acc0; acc3 = acc0;
#pragma unroll
    for (int kt = 0; kt < 2; kt++) {
        f16x8 afrag = *(const f16x8*)&hh[(r0 + m) * HSTR + kt * 32 + q * 8];
        f16x8 b0 = *(const f16x8*)&wgp[((kt * 4 + 0) << 9) + l * 8];
        f16x8 b1 = *(const f16x8*)&wgp[((kt * 4 + 1) << 9) + l * 8];
        f16x8 b2 = *(const f16x8*)&wgp[((kt * 4 + 2) << 9) + l * 8];
        f16x8 b3f = *(const f16x8*)&wgp[((kt * 4 + 3) << 9) + l * 8];
        acc0 = __builtin_amdgcn_mfma_f32_16x16x32_f16(afrag, b0, acc0, 0, 0, 0);
        acc1 = __builtin_amdgcn_mfma_f32_16x16x32_f16(afrag, b1, acc1, 0, 0, 0);
        acc2 = __builtin_amdgcn_mfma_f32_16x16x32_f16(afrag, b2, acc2, 0, 0, 0);
        acc3 = __builtin_amdgcn_mfma_f32_16x16x32_f16(afrag, b3f, acc3, 0, 0, 0);
    }
    {
        float e1[4] = {0.f, 0.f, 0.f, 0.f}, e2[4] = {0.f, 0.f, 0.f, 0.f};
#pragma unroll
        for (int c = 0; c < 4; c++) {
            const f32x4* ac = (c == 0) ? &acc0 : (c == 1) ? &acc1 : (c == 2) ? &acc2 : &acc3;
            float a1 = av[16 * c + m];
            float d1 = ad[16 * c + m];
#pragma unroll
            for (int reg = 0; reg < 4; reg++) {
                float g = (*ac)[reg];
                e1[reg] = fmaf(g, a1, e1[reg]);
                e2[reg] = fmaf(g, d1, e2[reg]);
                xw[(size_t)(v0 + r0 + q * 4 + reg) * 64 + 16 * c + m] = (f16)g;
            }
        }
#pragma unroll
        for (int reg = 0; reg < 4; reg++) {
            e1[reg] += __shfl_xor(e1[reg], 1); e1[reg] += __shfl_xor(e1[reg], 2);
            e1[reg] += __shfl_xor(e1[reg], 4); e1[reg] += __shfl_xor(e1[reg], 8);
            e2[reg] += __shfl_xor(e2[reg], 1); e2[reg] += __shfl_xor(e2[reg], 2);
            e2[reg] += __shfl_xor(e2[reg], 4); e2[reg] += __shfl_xor(e2[reg], 8);
        }
        if (m == 0) {
#pragma unroll
            for (int reg = 0; reg < 4; reg++) {
                es[v0 + r0 + q * 4 + reg] = e1[reg];
                ed[v0 + r0 + q * 4 + reg] = e2[reg];
            }
        }
    }
}

// ---------------- GAT edge softmax weights, normalization folded in ----------------
__global__ void gat_w_k(const float* __restrict__ es, const float* __restrict__ ed,
                        const int* __restrict__ rp, const int* __restrict__ col,
                        f16* __restrict__ ewi, float* __restrict__ wsi) {
    int v = blockIdx.x * 256 + threadIdx.x;
    if (v >= NN) return;
    float edv = ed[v];
    float eself = lrelu(es[v] + edv, 0.2f);
    float m = eself;
    int s = rp[v], e = rp[v + 1];
    int i = s;
    float lg[32];
    for (; i + 4 <= e; i += 4) {
        int u0 = col[i], u1 = col[i + 1], u2 = col[i + 2], u3 = col[i + 3];
        float t0 = lrelu(es[u0] + edv, 0.2f);
        float t1 = lrelu(es[u1] + edv, 0.2f);
        float t2 = lrelu(es[u2] + edv, 0.2f);
        float t3 = lrelu(es[u3] + edv, 0.2f);
        int k = i - s;
        if (k + 3 < 32) { lg[k] = t0; lg[k + 1] = t1; lg[k + 2] = t2; lg[k + 3] = t3; }
        m = fmaxf(m, fmaxf(fmaxf(t0, t1), fmaxf(t2, t3)));
    }
    for (; i < e; i++) {
        float t = lrelu(es[col[i]] + edv, 0.2f);
        int k = i - s;
        if (k < 32) lg[k] = t;
        m = fmaxf(m, t);
    }
    float wsl = __expf(eself - m);
    float den = wsl;
    for (i = s; i < e; i++) {
        int k = i - s;
        float t = (k < 32) ? lg[k] : lrelu(es[col[i]] + edv, 0.2f);
        float w = __expf(t - m);
        if (k < 32) lg[k] = w;
        den += w;
    }
    float inv = 1.f / den;
    for (i = s; i < e; i++) {
        int k = i - s;
        float w = (k < 32) ? lg[k] : __expf(lrelu(es[col[i]] + edv, 0.2f) - m);
        ewi[i] = (f16)(w * inv);
    }
    wsi[v] = wsl * inv;
}

// ---------------- edge-parallel GAT aggregation + piece-mean pooling ----------------
__global__ __launch_bounds__(256) void gat_agg_pool_k(const f16* __restrict__ y, const int* __restrict__ rp,
                                                      const int* __restrict__ col, const f16* __restrict__ ewi,
                                                      const float* __restrict__ wsi,
                                                      const float* __restrict__ bias, float* __restrict__ pooled) {
    __shared__ float sred[32 * 68];
    const int g = blockIdx.x;
    const int tid = threadIdx.x;
    const int idx = tid & 7;
    const int slot = tid >> 3;
    const f16x8* y8 = (const f16x8*)y;
    float acc[8];
#pragma unroll
    for (int j = 0; j < 8; j++) acc[j] = 0.f;

#pragma unroll
    for (int pass = 0; pass < 4; pass++) {
        const int v = g * 128 + pass * 32 + slot;
        float ws = wsi[v];
        f16x8 self = y8[(size_t)v * 8 + idx];
#pragma unroll
        for (int j = 0; j < 8; j++) acc[j] = fmaf(ws, (float)self[j], acc[j]);
    }

    const int s = rp[g * 128];
    const int e = rp[g * 128 + 128];
    int i = s + slot;
    for (; i + 96 < e; i += 128) {
        int u0 = col[i], u1 = col[i + 32], u2 = col[i + 64], u3 = col[i + 96];
        float w0 = (float)ewi[i], w1 = (float)ewi[i + 32], w2 = (float)ewi[i + 64], w3 = (float)ewi[i + 96];
        f16x8 a0 = y8[(size_t)u0 * 8 + idx];
        f16x8 a1 = y8[(size_t)u1 * 8 + idx];
        f16x8 a2 = y8[(size_t)u2 * 8 + idx];
        f16x8 a3 = y8[(size_t)u3 * 8 + idx];
#pragma unroll
        for (int j = 0; j < 8; j++)
            acc[j] = fmaf(w0, (float)a0[j], fmaf(w1, (float)a1[j], fmaf(w2, (float)a2[j], fmaf(w3, (float)a3[j], acc[j]))));
    }
    for (; i < e; i += 32) {
        int u = col[i];
        float w = (float)ewi[i];
        f16x8 a = y8[(size_t)u * 8 + idx];
#pragma unroll
        for (int j = 0; j < 8; j++) acc[j] = fmaf(w, (float)a[j], acc[j]);
    }

#pragma unroll
    for (int j = 0; j < 8; j++) sred[slot * 68 + idx * 8 + j] = acc[j];
    __syncthreads();
    if (tid < 64) {
        float s2 = 0.f;
#pragma unroll
        for (int k = 0; k < 32; k++) s2 += sred[k * 68 + tid];
        pooled[(size_t)g * 64 + tid] = s2 * (1.f / 128.f) + bias[tid];
    }
}

// ---------------- pooling (cross) ----------------
__global__ void pool_cross_k(const float* __restrict__ in, float* __restrict__ out) {
    int gid = blockIdx.x * 64 + threadIdx.x;
    if (gid >= BB * 64) return;
    int f = gid & 63, b = gid >> 6;
    const float* p = in + (size_t)b * CCROSS * 64 + f;
    float s = 0.f;
#pragma unroll
    for (int i = 0; i < CCROSS; i++) s += p[(size_t)i * 64];
    out[gid] = s * (1.f / 32.f);
}

// ---------------- GAT input gemm (fp32, small cross-graph path) ----------------
template <int KIN, int KOUT>
__global__ void gat_gemm_k(const float* __restrict__ x, const float* __restrict__ W,
                           float* __restrict__ y, const float* __restrict__ av, const float* __restrict__ ad,
                           float* __restrict__ es, float* __restrict__ ed, int n) {
    int v = blockIdx.x * 256 + threadIdx.x;
    if (v >= n) return;
    const float* xr = x + (size_t)v * KIN;
    float acc[KOUT];
#pragma unroll
    for (int j = 0; j < KOUT; j++) acc[j] = 0.f;
#pragma unroll 2
    for (int k = 0; k < KIN; k++) {
        float xv = xr[k];
#pragma unroll
        for (int j = 0; j < KOUT; j++) acc[j] = fmaf(xv, W[k * KOUT + j], acc[j]);
    }
    float e1 = 0.f, e2 = 0.f;
    float4* y4 = (float4*)(y + (size_t)v * KOUT);
#pragma unroll
    for (int j4 = 0; j4 < KOUT / 4; j4++) {
        float4 t;
        t.x = acc[4 * j4 + 0]; t.y = acc[4 * j4 + 1]; t.z = acc[4 * j4 + 2]; t.w = acc[4 * j4 + 3];
        y4[j4] = t;
        e1 = fmaf(t.x, av[4 * j4 + 0], e1); e1 = fmaf(t.y, av[4 * j4 + 1], e1);
        e1 = fmaf(t.z, av[4 * j4 + 2], e1); e1 = fmaf(t.w, av[4 * j4 + 3], e1);
        e2 = fmaf(t.x, ad[4 * j4 + 0], e2); e2 = fmaf(t.y, ad[4 * j4 + 1], e2);
        e2 = fmaf(t.z, ad[4 * j4 + 2], e2); e2 = fmaf(t.w, ad[4 * j4 + 3], e2);
    }
    es[v] = e1; ed[v] = e2;
}

// ---------------- dense cross-graph GAT ----------------
__global__ void cross_att_k(const float* __restrict__ xw, const float* __restrict__ es,
                            const float* __restrict__ ed, const float* __restrict__ bg,
                            float* __restrict__ out) {
    int gid = blockIdx.x * 256 + threadIdx.x;
    if (gid >= BB * CCROSS * 64) return;
    int f = gid & 63;
    int d = (gid >> 6) & 31;
    int g = gid >> 11;
    int base = g * CCROSS;
    float edd = ed[base + d];
    float m = -1e30f;
#pragma unroll
    for (int s = 0; s < CCROSS; s++) {
        float e = lrelu(es[base + s] + edd, 0.2f);
        m = fmaxf(m, e);
    }
    float den = 0.f, acc = 0.f;
#pragma unroll
    for (int s = 0; s < CCROSS; s++) {
        float e = lrelu(es[base + s] + edd, 0.2f);
        float w = __expf(e - m) * ((s == d) ? 1.f : 2.f);
        den += w;
        acc = fmaf(w, xw[(size_t)(base + s) * 64 + f], acc);
    }
    out[gid] = acc / den + bg[f];
}

// ---------------- fused conv branch (transposed f16 stages + dot2, 512 blocks) ----------------
__global__ __launch_bounds__(256) void conv_fused_k(
        const float* __restrict__ pts, const float* __restrict__ c1W, const float* __restrict__ c1b,
        const float* __restrict__ g1, const float* __restrict__ be1,
        const f16* __restrict__ w2p, const float* __restrict__ c2b,
        const float* __restrict__ g2, const float* __restrict__ be2,
        const f16* __restrict__ w3pc, const float* __restrict__ c3b,
        float* __restrict__ partials) {
    __shared__ __align__(16) float s0[3 * 264];
    __shared__ __align__(16) f16 s1T[132 * 32];
    __shared__ __align__(16) f16 s2T[66 * 64];
    __shared__ float sred[256];

    const int b = blockIdx.x >> 3;
    const int q = blockIdx.x & 7;
    const int tid = threadIdx.x;
    const float bnscale = 0.99999500003749968f;

    const int lo0 = 256 * q - 7;
    for (int t = tid; t < 3 * 263; t += 256) {
        int c = t / 263, j = t - c * 263;
        int p = lo0 + j;
        s0[c * 264 + j] = (p >= 0 && p < PP) ? pts[((size_t)b * 3 + c) * PP + p] : 0.f;
    }
    __syncthreads();

    {
        const int ch = tid & 31;
        const int j0 = tid >> 5;
        float wv[9];
        const float* wg = c1W + ch * 9;
#pragma unroll
        for (int t = 0; t < 9; t++) wv[t] = wg[t];
        const float bs = c1b[ch];
        const float gs = g1[ch] * bnscale;
        const float bt = be1[ch];
        const int lo1 = 128 * q - 3;
        for (int j = j0; j < 131; j += 8) {
            int p1 = lo1 + j;
            float v = 0.f;
            if (p1 >= 0 && p1 < 1024) {
                const float* x0 = s0 + 2 * j;
                float a0 = bs, a1 = 0.f, a2 = 0.f;
#pragma unroll
                for (int c = 0; c < 3; c++) {
                    float2 x01 = *(const float2*)(x0 + c * 264);
                    float x2v = x0[c * 264 + 2];
                    a0 = fmaf(x01.x, wv[c * 3 + 0], a0);
                    a1 = fmaf(x01.y, wv[c * 3 + 1], a1);
                    a2 = fmaf(x2v, wv[c * 3 + 2], a2);
                }
                float acc = a0 + a1 + a2;
                acc = lrelu(acc, 0.01f);
                v = fmaf(acc, gs, bt);
            }
            s1T[j * 32 + ch] = (f16)v;
        }
    }
    __syncthreads();

    {
        const int ch = tid & 63;
        const int jg = tid >> 6;
        unsigned wr[48];
        const uint4* wp = (const uint4*)(w2p + (size_t)ch * 96);
#pragma unroll
        for (int t = 0; t < 12; t++) {
            uint4 u = wp[t];
            wr[4 * t + 0] = u.x; wr[4 * t + 1] = u.y; wr[4 * t + 2] = u.z; wr[4 * t + 3] = u.w;
        }
        const float bs = c2b[ch];
        const float gs = g2[ch] * bnscale;
        const float bt = be2[ch];
        const int lo2v = 64 * q - 1;
        for (int j = jg; j < 65; j += 4) {
            float ak[3] = {bs, 0.f, 0.f};
#pragma unroll
            for (int k = 0; k < 3; k++) {
                const uint4* xp = (const uint4*)(s1T + (2 * j + k) * 32);
                uint4 x0 = xp[0], x1 = xp[1], x2 = xp[2], x3 = xp[3];
                float a = ak[k];
                a = dot2f(x0.x, wr[k * 16 + 0], a);
                a = dot2f(x0.y, wr[k * 16 + 1], a);
                a = dot2f(x0.z, wr[k * 16 + 2], a);
                a = dot2f(x0.w, wr[k * 16 + 3], a);
                a = dot2f(x1.x, wr[k * 16 + 4], a);
                a = dot2f(x1.y, wr[k * 16 + 5], a);
                a = dot2f(x1.z, wr[k * 16 + 6], a);
                a = dot2f(x1.w, wr[k * 16 + 7], a);
                a = dot2f(x2.x, wr[k * 16 + 8], a);
                a = dot2f(x2.y, wr[k * 16 + 9], a);
                a = dot2f(x2.z, wr[k * 16 + 10], a);
                a = dot2f(x2.w, wr[k * 16 + 11], a);
                a = dot2f(x3.x, wr[k * 16 + 12], a);
                a = dot2f(x3.y, wr[k * 16 + 13], a);
                a = dot2f(x3.z, wr[k * 16 + 14], a);
                a = dot2f(x3.w, wr[k * 16 + 15], a);
                ak[k] = a;
            }
            float acc = ak[0] + ak[1] + ak[2];
            int p2 = lo2v + j;
            float v = 0.f;
            if (p2 >= 0 && p2 < 512) v = fmaf(lrelu(acc, 0.01f), gs, bt);
            s2T[j * 64 + ch] = (f16)v;
        }
    }
    __syncthreads();

    {
        const int ch = tid & 63;
        const int jg = tid >> 6;
        unsigned wr[96];
        const uint4* wp = (const uint4*)(w3pc + (size_t)ch * 192);
#pragma unroll
        for (int t = 0; t < 24; t++) {
            uint4 u = wp[t];
            wr[4 * t + 0] = u.x; wr[4 * t + 1] = u.y; wr[4 * t + 2] = u.z; wr[4 * t + 3] = u.w;
        }
        const float bs = c3b[ch];
        float psum = 0.f;
        for (int j = jg; j < 32; j += 4) {
            float ak[3] = {bs, 0.f, 0.f};
#pragma unroll
            for (int k = 0; k < 3; k++) {
                const uint4* xp = (const uint4*)(s2T + (2 * j + k) * 64);
                float a = ak[k];
#pragma unroll
                for (int t = 0; t < 8; t++) {
                    uint4 xv = xp[t];
                    a = dot2f(xv.x, wr[k * 32 + 4 * t + 0], a);
                    a = dot2f(xv.y, wr[k * 32 + 4 * t + 1], a);
                    a = dot2f(xv.z, wr[k * 32 + 4 * t + 2], a);
                    a = dot2f(xv.w, wr[k * 32 + 4 * t + 3], a);
                }
                ak[k] = a;
            }
            psum += lrelu(ak[0] + ak[1] + ak[2], 0.01f);
        }
        sred[tid] = psum;
    }
    __syncthreads();
    if (tid < 64) {
        float s = sred[tid] + sred[tid + 64] + sred[tid + 128] + sred[tid + 192];
        partials[((size_t)b * 8 + q) * 64 + tid] = s;
    }
}

// ---------------- head ----------------
__global__ void head_k(const float* __restrict__ hG, const float* __restrict__ partials,
                       const float* __restrict__ Wl2, const float* __restrict__ bl2,
                       const float* __restrict__ Wl3, const float* __restrict__ bl3,
                       float* __restrict__ out) {
    int b = blockIdx.x;
    int f = threadIdx.x;  // 64
    __shared__ float sh[64];
    float p = 0.f;
#pragma unroll
    for (int q = 0; q < 8; q++) p += partials[((size_t)b * 8 + q) * 64 + f];
    float h = hG[b * 64 + f] + p * (1.f / 256.f);
    sh[f] = h;
    __syncthreads();
    float acc = bl2[f];
#pragma unroll
    for (int k = 0; k < 64; k++) acc = fmaf(sh[k], Wl2[k * 64 + f], acc);
    acc = lrelu(acc, 0.01f);
    float pr = acc * Wl3[f];
#pragma unroll
    for (int off = 32; off > 0; off >>= 1) pr += __shfl_down(pr, off, 64);
    if (f == 0) out[b] = 1.f / (1.f + __expf(-(pr + bl3[0])));
}

extern "C" void kernel_launch(void* const* d_in, const int* in_sizes, int n_in,
                              void* d_out, int out_size, void* d_ws, size_t ws_size,
                              hipStream_t stream) {
    const float* x = (const float*)d_in[0];
    const int* ei = (const int*)d_in[1];
    const float* points = (const float*)d_in[2];
    const float* W1 = (const float*)d_in[3];
    const float* b1 = (const float*)d_in[4];
    const float* W2 = (const float*)d_in[5];
    const float* b2 = (const float*)d_in[6];
    const float* W3 = (const float*)d_in[7];
    const float* b3 = (const float*)d_in[8];
    const float* Wg1 = (const float*)d_in[9];
    const float* asrc1 = (const float*)d_in[10];
    const float* adst1 = (const float*)d_in[11];
    const float* bg1 = (const float*)d_in[12];
    const float* Wg2 = (const float*)d_in[13];
    const float* asrc2 = (const float*)d_in[14];
    const float* adst2 = (const float*)d_in[15];
    const float* bg2 = (const float*)d_in[16];
    const float* c1W = (const float*)d_in[17];
    const float* c1b = (const float*)d_in[18];
    const float* g1 = (const float*)d_in[19];
    const float* be1 = (const float*)d_in[20];
    const float* c2W = (const float*)d_in[21];
    const float* c2b = (const float*)d_in[22];
    const float* g2 = (const float*)d_in[23];
    const float* be2 = (const float*)d_in[24];
    const float* c3W = (const float*)d_in[25];
    const float* c3b = (const float*)d_in[26];
    const float* Wl2 = (const float*)d_in[27];
    const float* bl2 = (const float*)d_in[28];
    const float* Wl3 = (const float*)d_in[29];
    const float* bl3 = (const float*)d_in[30];

    const int* src = ei;
    const int* dst = ei + EE;

    // ---- workspace carve-up ----
    char* w = (char*)d_ws;
    size_t off = 0;
    auto A = [&](size_t bytes) -> void* {
        void* p = w + off;
        off = (off + bytes + 255) & ~(size_t)255;
        return p;
    };
    int* colb = (int*)A((size_t)EE * 4);
    int* rp = (int*)A((size_t)(NN + 1) * 4);
    int* gcnt = (int*)A(NBUCK * 4);
    int* bbase = (int*)A(NBUCK * 4);
    float* dinv = (float*)A((size_t)NN * 4);
    float* bufA = (float*)A((size_t)NN * 64 * 4);
    f16* bufH1 = (f16*)A((size_t)NN * 64 * 2);
    f16* bufH2 = (f16*)A((size_t)NN * 64 * 2);
    f16* ewi = (f16*)A((size_t)EE * 2);
    float* wsi = (float*)A((size_t)NN * 4);
    float* es = (float*)A((size_t)NN * 4);
    float* edv = (float*)A((size_t)NN * 4);
    f16* w3p = (f16*)A(4096 * 2);
    f16* wgp = (f16*)A(4096 * 2);
    f16* wc2p = (f16*)A(64 * 96 * 2);
    f16* wc3p = (f16*)A(64 * 192 * 2);
    float* pooled = (float*)A((size_t)BB * CCROSS * 64 * 4);
    float* xw2 = (float*)A((size_t)BB * CCROSS * 64 * 4);
    float* es2 = (float*)A((size_t)BB * CCROSS * 4);
    float* ed2 = (float*)A((size_t)BB * CCROSS * 4);
    float* crosso = (float*)A((size_t)BB * CCROSS * 64 * 4);
    float* hG = (float*)A((size_t)BB * 64 * 4);
    float* partials = (float*)A((size_t)BB * 8 * 64 * 4);

    unsigned* buckets = (unsigned*)bufA;   // aliases bufA; dead after CSR build

    // ---- CSR build (bucketed) ----
    hipMemsetAsync(gcnt, 0, NBUCK * 4, stream);
    bucket_a_k<<<EE / 8192, 256, 0, stream>>>(src, dst, buckets, gcnt);
    bucket_scan_k<<<1, 256, 0, stream>>>(gcnt, bbase, rp);
    bucket_b_k<<<NBUCK, 256, 0, stream>>>(buckets, gcnt, bbase, rp, dinv, colb);

    // ---- points branch + weight packing ----
    pack_c2_k<<<24, 256, 0, stream>>>(c2W, wc2p);
    pack_c3_k<<<48, 256, 0, stream>>>(c3W, wc3p);
    conv_fused_k<<<BB * 8, 256, 0, stream>>>(points, c1W, c1b, g1, be1, wc2p, c2b, g2, be2, wc3p, c3b, partials);
    pack_w_k<<<16, 256, 0, stream>>>(W3, w3p);
    pack_w_k<<<16, 256, 0, stream>>>(Wg1, wgp);

    // ---- GCN 1/2 (fused agg+gemm), GCN3+GAT gemm (row-parallel gather fused into MFMA kernel) ----
    zprep_k<<<NN / 256, 256, 0, stream>>>(x, dinv, bufH1);                               // H1 = z1 [NN x 32h]
    fused_agg_gemm_k<19, 32, 0><<<NN / 64, 256, 0, stream>>>(bufH1, rp, colb, W1, dinv, b1, bufH2);  // H2 = z2
    fused_agg_gemm_k<32, 64, 1><<<NN / 64, 256, 0, stream>>>(bufH2, rp, colb, W2, dinv, b2, bufH1);  // H1 = z3
    gemm3_gat_k<<<NN / 64, 256, 0, stream>>>(bufH1, rp, colb, w3p, dinv, b3, wgp, asrc1, adst1,
                                             bufH2, es, edv);                            // H2 = xw, es/ed

    // ---- GAT 1 softmax (normalization folded) + edge-parallel aggregation+pooling ----
    gat_w_k<<<NN / 256, 256, 0, stream>>>(es, edv, rp, colb, ewi, wsi);
    gat_agg_pool_k<<<BB * CCROSS, 256, 0, stream>>>(bufH2, rp, colb, ewi, wsi, bg1, pooled);

    // ---- cross GAT -> pool cross ----
    gat_gemm_k<64, 64><<<(BB * CCROSS) / 256, 256, 0, stream>>>(pooled, Wg2, xw2, asrc2, adst2, es2, ed2, BB * CCROSS);
    cross_att_k<<<(BB * CCROSS * 64) / 256, 256, 0, stream>>>(xw2, es2, ed2, bg2, crosso);
    pool_cross_k<<<BB, 64, 0, stream>>>(crosso, hG);

    // ---- head ----
    head_k<<<BB, 64, 0, stream>>>(hG, partials, Wl2, bl2, Wl3, bl3, (float*)d_out);
}

// Round 7
// 461.898 us; speedup vs baseline: 1.2387x; 1.0402x over previous
//
#include <hip/hip_runtime.h>
#include <cstdint>
#include <cstddef>

#define NN 262144
#define EE 2097152
#define BB 64
#define CCROSS 32
#define PCC 128
#define PP 2048
#define NBUCK 256
#define BCAP 12288

typedef _Float16 f16;
typedef __attribute__((ext_vector_type(2))) _Float16 f16x2;
typedef __attribute__((ext_vector_type(4))) _Float16 f16x4;
typedef __attribute__((ext_vector_type(8))) _Float16 f16x8;
typedef __attribute__((ext_vector_type(4))) float f32x4;

static __device__ __forceinline__ float lrelu(float x, float s) { return x > 0.f ? x : s * x; }

#if __has_builtin(__builtin_amdgcn_fdot2)
static __device__ __forceinline__ float dot2f(unsigned x, unsigned w, float c) {
    return __builtin_amdgcn_fdot2(__builtin_bit_cast(f16x2, x), __builtin_bit_cast(f16x2, w), c, false);
}
#else
static __device__ __forceinline__ float dot2f(unsigned x, unsigned w, float c) {
    f16x2 a = __builtin_bit_cast(f16x2, x);
    f16x2 b = __builtin_bit_cast(f16x2, w);
    return fmaf((float)a[0], (float)b[0], fmaf((float)a[1], (float)b[1], c));
}
#endif

// ---------------- bucketed CSR build ----------------
__global__ __launch_bounds__(256) void bucket_a_k(const int* __restrict__ src, const int* __restrict__ dst,
                                                  unsigned* __restrict__ buckets, int* __restrict__ gcnt) {
    __shared__ int hist[NBUCK];
    __shared__ int base[NBUCK];
    __shared__ unsigned short rankbuf[8192];
    const int tid = threadIdx.x;
    const int e0 = blockIdx.x * 8192;
    hist[tid] = 0;
    __syncthreads();
    for (int i = tid; i < 8192; i += 256) {
        int d = dst[e0 + i];
        rankbuf[i] = (unsigned short)atomicAdd(&hist[d >> 10], 1);
    }
    __syncthreads();
    base[tid] = tid * BCAP + atomicAdd(&gcnt[tid], hist[tid]);
    __syncthreads();
    for (int i = tid; i < 8192; i += 256) {
        int s = src[e0 + i];
        int d = dst[e0 + i];
        int b = d >> 10;
        buckets[base[b] + rankbuf[i]] = ((unsigned)s << 10) | (unsigned)(d & 1023);
    }
}

// bucket_b with the global scan of gcnt folded in (each block redundantly scans 256 entries)
__global__ __launch_bounds__(256) void bucket_b_k(const unsigned* __restrict__ buckets, const int* __restrict__ gcnt,
                                                  int* __restrict__ rp,
                                                  float* __restrict__ dinv, int* __restrict__ col) {
    __shared__ int cnt[1024];
    __shared__ int scan[1024];
    __shared__ int wsum[256];
    const int b = blockIdx.x;
    const int tid = threadIdx.x;

    // exclusive scan of gcnt to get this bucket's global base
    wsum[tid] = gcnt[tid];
    __syncthreads();
    for (int off = 1; off < 256; off <<= 1) {
        int t = (tid >= off) ? wsum[tid - off] : 0;
        __syncthreads();
        wsum[tid] += t;
        __syncthreads();
    }
    const int gb = wsum[b] - gcnt[b];
    if (b == 0 && tid == 0) rp[NN] = EE;

    int n = gcnt[b];
    if (n > BCAP) n = BCAP;
    const unsigned* eb = buckets + (size_t)b * BCAP;
    for (int i = tid; i < 1024; i += 256) cnt[i] = 0;
    __syncthreads();
    for (int i = tid; i < n; i += 256) atomicAdd(&cnt[eb[i] & 1023], 1);
    __syncthreads();
    int b4 = tid * 4;
    int c0 = cnt[b4], c1 = cnt[b4 + 1], c2 = cnt[b4 + 2], c3 = cnt[b4 + 3];
    int tsum = c0 + c1 + c2 + c3;
    wsum[tid] = tsum;
    __syncthreads();
    for (int off = 1; off < 256; off <<= 1) {
        int t = (tid >= off) ? wsum[tid - off] : 0;
        __syncthreads();
        wsum[tid] += t;
        __syncthreads();
    }
    int excl = wsum[tid] - tsum;
    scan[b4] = excl;
    scan[b4 + 1] = excl + c0;
    scan[b4 + 2] = excl + c0 + c1;
    scan[b4 + 3] = excl + c0 + c1 + c2;
    int vbase = b * 1024 + b4;
    rp[vbase + 0] = gb + scan[b4 + 0];
    rp[vbase + 1] = gb + scan[b4 + 1];
    rp[vbase + 2] = gb + scan[b4 + 2];
    rp[vbase + 3] = gb + scan[b4 + 3];
    dinv[vbase + 0] = rsqrtf((float)(c0 + 1));
    dinv[vbase + 1] = rsqrtf((float)(c1 + 1));
    dinv[vbase + 2] = rsqrtf((float)(c2 + 1));
    dinv[vbase + 3] = rsqrtf((float)(c3 + 1));
    __syncthreads();
    for (int i = tid; i < 1024; i += 256) cnt[i] = 0;
    __syncthreads();
    for (int i = tid; i < n; i += 256) {
        unsigned p = eb[i];
        int dl = p & 1023;
        int r = atomicAdd(&cnt[dl], 1);
        col[gb + scan[dl] + r] = (int)(p >> 10);
    }
}

// ---------------- z-prep ----------------
__global__ void zprep_k(const float* __restrict__ x, const float* __restrict__ dinv, f16* __restrict__ z) {
    int v = blockIdx.x * 256 + threadIdx.x;
    if (v >= NN) return;
    float dv = dinv[v];
    const float* xr = x + (size_t)v * 19;
    float vv[20];
#pragma unroll
    for (int k = 0; k < 19; k++) vv[k] = dv * xr[k];
    vv[19] = 0.f;
    f16x4* zr = (f16x4*)(z + (size_t)v * 32);
#pragma unroll
    for (int c = 0; c < 5; c++) {
        f16x4 t = {(f16)vv[4 * c], (f16)vv[4 * c + 1], (f16)vv[4 * c + 2], (f16)vv[4 * c + 3]};
        zr[c] = t;
    }
    f16x4 zz = {(f16)0.f, (f16)0.f, (f16)0.f, (f16)0.f};
#pragma unroll
    for (int c = 5; c < 8; c++) zr[c] = zz;
}

// ---------------- fused agg (64B fp16 rows) + gemm, wide-gather version ----------------
#define ZSTR1 36
template <int KINR, int KOUT, int ACT>
__global__ __launch_bounds__(256) void fused_agg_gemm_k(const f16* __restrict__ z, const int* __restrict__ rp,
                                                        const int* __restrict__ col, const float* __restrict__ Wg,
                                                        const float* __restrict__ dinv, const float* __restrict__ bias,
                                                        f16* __restrict__ zout) {
    constexpr int NO = KOUT / 4;
    __shared__ float Wl[32 * KOUT];
    __shared__ float zrow[64 * ZSTR1];
    const int tid = threadIdx.x;
    for (int i = tid; i < 32 * KOUT; i += 256) Wl[i] = (i < KINR * KOUT) ? Wg[i] : 0.f;

    const int r = tid >> 2;
    const int idx = tid & 3;
    const int v = blockIdx.x * 64 + r;
    const f16x8* z8 = (const f16x8*)z;
    f16x8 a = z8[(size_t)v * 4 + idx];
    float acc8[8];
#pragma unroll
    for (int j = 0; j < 8; j++) acc8[j] = (float)a[j];
    int st = rp[v], e = rp[v + 1];
    int i = st;
    for (; i + 4 <= e; i += 4) {
        int u0 = col[i], u1 = col[i + 1], u2 = col[i + 2], u3 = col[i + 3];
        f16x8 a0 = z8[(size_t)u0 * 4 + idx];
        f16x8 a1 = z8[(size_t)u1 * 4 + idx];
        f16x8 a2 = z8[(size_t)u2 * 4 + idx];
        f16x8 a3 = z8[(size_t)u3 * 4 + idx];
#pragma unroll
        for (int j = 0; j < 8; j++)
            acc8[j] += ((float)a0[j] + (float)a1[j]) + ((float)a2[j] + (float)a3[j]);
    }
    for (; i < e; i++) {
        f16x8 aa = z8[(size_t)col[i] * 4 + idx];
#pragma unroll
        for (int j = 0; j < 8; j++) acc8[j] += (float)aa[j];
    }
    float4 s0, s1;
    s0.x = acc8[0]; s0.y = acc8[1]; s0.z = acc8[2]; s0.w = acc8[3];
    s1.x = acc8[4]; s1.y = acc8[5]; s1.z = acc8[6]; s1.w = acc8[7];
    *(float4*)&zrow[r * ZSTR1 + idx * 8] = s0;
    *(float4*)&zrow[r * ZSTR1 + idx * 8 + 4] = s1;
    __syncthreads();

    float acc[NO];
#pragma unroll
    for (int j = 0; j < NO; j++) acc[j] = 0.f;
#pragma unroll 4
    for (int k = 0; k < 32; k++) {
        float zv = zrow[r * ZSTR1 + k];
        const float* wr = Wl + k * KOUT + NO * idx;
#pragma unroll
        for (int j = 0; j < NO; j++) acc[j] = fmaf(zv, wr[j], acc[j]);
    }
    float dv = dinv[v];
    f16 hv[NO];
#pragma unroll
    for (int j = 0; j < NO; j++) {
        float o = dv * acc[j] + bias[NO * idx + j];
        o = (ACT == 0) ? fmaxf(o, 0.f) : lrelu(o, 0.01f);
        hv[j] = (f16)(o * dv);
    }
    if constexpr (NO == 8) {
        f16x8 h = {hv[0], hv[1], hv[2], hv[3], hv[4], hv[5], hv[6], hv[7]};
        *(f16x8*)(zout + (size_t)v * KOUT + NO * idx) = h;
    } else {
        f16x8 h0 = {hv[0], hv[1], hv[2], hv[3], hv[4], hv[5], hv[6], hv[7]};
        f16x8 h1 = {hv[8], hv[9], hv[10], hv[11], hv[12], hv[13], hv[14], hv[15]};
        f16x8* yo = (f16x8*)(zout + (size_t)v * KOUT + NO * idx);
        yo[0] = h0; yo[1] = h1;
    }
}

// ---------------- pack all weights in one kernel ----------------
// o in [0,4096): W3 -> w3p ; [4096,8192): Wg1 -> wgp ; [8192,14336): c2W -> wc2p ; [14336,26624): c3W -> wc3p
__global__ void pack_all_k(const float* __restrict__ W3, const float* __restrict__ Wg1,
                           const float* __restrict__ c2W, const float* __restrict__ c3W,
                           f16* __restrict__ w3p, f16* __restrict__ wgp,
                           f16* __restrict__ wc2p, f16* __restrict__ wc3p) {
    int o = blockIdx.x * 256 + threadIdx.x;
    if (o < 8192) {
        int oo = o & 4095;
        const float* W = (o < 4096) ? W3 : Wg1;
        f16* out = (o < 4096) ? w3p : wgp;
        int frag = oo >> 9;
        int kt = frag >> 2;
        int c = frag & 3;
        int idx = oo & 511;
        int l = idx >> 3;
        int j = idx & 7;
        int k = kt * 32 + ((l >> 4) << 3) + j;
        int n = 16 * c + (l & 15);
        out[oo] = (f16)W[k * 64 + n];
    } else if (o < 14336) {
        int oo = o - 8192;
        int ch = oo / 96, r = oo - ch * 96;
        int k = r >> 5, ci = r & 31;
        wc2p[oo] = (f16)c2W[ch * 96 + ci * 3 + k];
    } else if (o < 26624) {
        int oo = o - 14336;
        int ch = oo / 192, r = oo - ch * 192;
        int k = r >> 6, ci = r & 63;
        wc3p[oo] = (f16)c3W[ch * 192 + ci * 3 + k];
    }
}

// ---------------- fused: agg(z3) gather -> LDS; h3 = lrelu(dinv*(agg@W3)+b3); xw = h3@Wg1; es/ed ----------------
#define HSTR 72
__global__ __launch_bounds__(256) void gemm3_gat_k(const f16* __restrict__ y, const int* __restrict__ rp,
                                                   const int* __restrict__ col, const f16* __restrict__ w3p,
                                                   const float* __restrict__ dinv, const float* __restrict__ b3,
                                                   const f16* __restrict__ wgp, const float* __restrict__ av,
                                                   const float* __restrict__ ad, f16* __restrict__ xw,
                                                   float* __restrict__ es, float* __restrict__ ed) {
    __shared__ f16 zin[64 * HSTR];
    __shared__ f16 hh[64 * HSTR];
    const int tid = threadIdx.x;
    const int v0 = blockIdx.x * 64;
    {
        const int row = tid >> 2;
        const int idx = tid & 3;
        const int v = v0 + row;
        const f16x8* y8 = (const f16x8*)y;
        f16x8 s0 = y8[(size_t)v * 8 + idx * 2];
        f16x8 s1 = y8[(size_t)v * 8 + idx * 2 + 1];
        float acc[16];
#pragma unroll
        for (int j = 0; j < 8; j++) { acc[j] = (float)s0[j]; acc[8 + j] = (float)s1[j]; }
        int s = rp[v], e = rp[v + 1];
        int i = s;
        for (; i + 4 <= e; i += 4) {
            int u0 = col[i], u1 = col[i + 1], u2 = col[i + 2], u3 = col[i + 3];
            f16x8 a0 = y8[(size_t)u0 * 8 + idx * 2];
            f16x8 a1 = y8[(size_t)u0 * 8 + idx * 2 + 1];
            f16x8 b0 = y8[(size_t)u1 * 8 + idx * 2];
            f16x8 b1 = y8[(size_t)u1 * 8 + idx * 2 + 1];
            f16x8 c0 = y8[(size_t)u2 * 8 + idx * 2];
            f16x8 c1 = y8[(size_t)u2 * 8 + idx * 2 + 1];
            f16x8 d0 = y8[(size_t)u3 * 8 + idx * 2];
            f16x8 d1 = y8[(size_t)u3 * 8 + idx * 2 + 1];
#pragma unroll
            for (int j = 0; j < 8; j++) {
                acc[j] += ((float)a0[j] + (float)b0[j]) + ((float)c0[j] + (float)d0[j]);
                acc[8 + j] += ((float)a1[j] + (float)b1[j]) + ((float)c1[j] + (float)d1[j]);
            }
        }
        for (; i < e; i++) {
            int u = col[i];
            f16x8 a0 = y8[(size_t)u * 8 + idx * 2];
            f16x8 a1 = y8[(size_t)u * 8 + idx * 2 + 1];
#pragma unroll
            for (int j = 0; j < 8; j++) { acc[j] += (float)a0[j]; acc[8 + j] += (float)a1[j]; }
        }
        f16x8 o0, o1;
#pragma unroll
        for (int j = 0; j < 8; j++) { o0[j] = (f16)acc[j]; o1[j] = (f16)acc[8 + j]; }
        *(f16x8*)&zin[row * HSTR + idx * 16] = o0;
        *(f16x8*)&zin[row * HSTR + idx * 16 + 8] = o1;
    }
    __syncthreads();

    const int w = tid >> 6;
    const int l = tid & 63;
    const int m = l & 15;
    const int q = l >> 4;
    const int r0 = 16 * w;

    f32x4 acc0 = {0.f, 0.f, 0.f, 0.f}, acc1 = acc0, acc2 = acc0, acc3 = acc0;
#pragma unroll
    for (int kt = 0; kt < 2; kt++) {
        f16x8 afrag = *(const f16x8*)&zin[(r0 + m) * HSTR + kt * 32 + q * 8];
        f16x8 b0 = *(const f16x8*)&w3p[((kt * 4 + 0) << 9) + l * 8];
        f16x8 b1 = *(const f16x8*)&w3p[((kt * 4 + 1) << 9) + l * 8];
        f16x8 b2 = *(const f16x8*)&w3p[((kt * 4 + 2) << 9) + l * 8];
        f16x8 b3f = *(const f16x8*)&w3p[((kt * 4 + 3) << 9) + l * 8];
        acc0 = __builtin_amdgcn_mfma_f32_16x16x32_f16(afrag, b0, acc0, 0, 0, 0);
        acc1 = __builtin_amdgcn_mfma_f32_16x16x32_f16(afrag, b1, acc1, 0, 0, 0);
        acc2 = __builtin_amdgcn_mfma_f32_16x16x32_f16(afrag, b2, acc2, 0, 0, 0);
        acc3 = __builtin_amdgcn_mfma_f32_16x16x32_f16(afrag, b3f, acc3, 0, 0, 0);
    }
    {
        float dv0 = dinv[v0 + r0 + q * 4 + 0];
        float dv1 = dinv[v0 + r0 + q * 4 + 1];
        float dv2 = dinv[v0 + r0 + q * 4 + 2];
        float dv3 = dinv[v0 + r0 + q * 4 + 3];
#pragma unroll
        for (int c = 0; c < 4; c++) {
            const f32x4* ac = (c == 0) ? &acc0 : (c == 1) ? &acc1 : (c == 2) ? &acc2 : &acc3;
            float bb = b3[16 * c + m];
            hh[(r0 + q * 4 + 0) * HSTR + 16 * c + m] = (f16)lrelu(dv0 * (*ac)[0] + bb, 0.01f);
            hh[(r0 + q * 4 + 1) * HSTR + 16 * c + m] = (f16)lrelu(dv1 * (*ac)[1] + bb, 0.01f);
            hh[(r0 + q * 4 + 2) * HSTR + 16 * c + m] = (f16)lrelu(dv2 * (*ac)[2] + bb, 0.01f);
            hh[(r0 + q * 4 + 3) * HSTR + 16 * c + m] = (f16)lrelu(dv3 * (*ac)[3] + bb, 0.01f);
        }
    }
    __syncthreads();

    acc0 = (f32x4){0.f, 0.f, 0.f, 0.f}; acc1 = acc0; acc2 = acc0; acc3 = acc0;
#pragma unroll
    for (int kt = 0; kt < 2; kt++) {
        f16x8 afrag = *(const f16x8*)&hh[(r0 + m) * HSTR + kt * 32 + q * 8];
        f16x8 b0 = *(const f16x8*)&wgp[((kt * 4 + 0) << 9) + l * 8];
        f16x8 b1 = *(const f16x8*)&wgp[((kt * 4 + 1) << 9) + l * 8];
        f16x8 b2 = *(const f16x8*)&wgp[((kt * 4 + 2) << 9) + l * 8];
        f16x8 b3f = *(const f16x8*)&wgp[((kt * 4 + 3) << 9) + l * 8];
        acc0 = __builtin_amdgcn_mfma_f32_16x16x32_f16(afrag, b0, acc0, 0, 0, 0);
        acc1 = __builtin_amdgcn_mfma_f32_16x16x32_f16(afrag, b1, acc1, 0, 0, 0);
        acc2 = __builtin_amdgcn_mfma_f32_16x16x32_f16(afrag, b2, acc2, 0, 0, 0);
        acc3 = __builtin_amdgcn_mfma_f32_16x16x32_f16(afrag, b3f, acc3, 0, 0, 0);
    }
    {
        float e1[4] = {0.f, 0.f, 0.f, 0.f}, e2[4] = {0.f, 0.f, 0.f, 0.f};
#pragma unroll
        for (int c = 0; c < 4; c++) {
            const f32x4* ac = (c == 0) ? &acc0 : (c == 1) ? &acc1 : (c == 2) ? &acc2 : &acc3;
            float a1 = av[16 * c + m];
            float d1 = ad[16 * c + m];
#pragma unroll
            for (int reg = 0; reg < 4; reg++) {
                float g = (*ac)[reg];
                e1[reg] = fmaf(g, a1, e1[reg]);
                e2[reg] = fmaf(g, d1, e2[reg]);
                xw[(size_t)(v0 + r0 + q * 4 + reg) * 64 + 16 * c + m] = (f16)g;
            }
        }
#pragma unroll
        for (int reg = 0; reg < 4; reg++) {
            e1[reg] += __shfl_xor(e1[reg], 1); e1[reg] += __shfl_xor(e1[reg], 2);
            e1[reg] += __shfl_xor(e1[reg], 4); e1[reg] += __shfl_xor(e1[reg], 8);
            e2[reg] += __shfl_xor(e2[reg], 1); e2[reg] += __shfl_xor(e2[reg], 2);
            e2[reg] += __shfl_xor(e2[reg], 4); e2[reg] += __shfl_xor(e2[reg], 8);
        }
        if (m == 0) {
#pragma unroll
            for (int reg = 0; reg < 4; reg++) {
                es[v0 + r0 + q * 4 + reg] = e1[reg];
                ed[v0 + r0 + q * 4 + reg] = e2[reg];
            }
        }
    }
}

// ---------------- fused GAT softmax + edge-parallel aggregation + piece-mean pooling ----------------
// Phase A: 128 threads, one dst-row each: per-row softmax (es gathers are L2-resident),
//          weights (normalization folded) -> LDS ewl[edge - sG] (f16), self -> wsl[row].
//          Overflow (group edges > 2048; ~never for Poisson(8)x128) spills to global ewg.
// Phase B: edge-parallel flat walk (32 slots x 8 feat-lanes), weights from LDS.
__global__ __launch_bounds__(256) void gat_aggw_pool_k(const f16* __restrict__ y, const int* __restrict__ rp,
                                                       const int* __restrict__ col,
                                                       const float* __restrict__ es, const float* __restrict__ ed,
                                                       const float* __restrict__ bias, f16* __restrict__ ewg,
                                                       float* __restrict__ pooled) {
    __shared__ float sred[32 * 68];
    __shared__ f16 ewl[2048];
    __shared__ float wsl[128];
    __shared__ int rpl[129];
    const int g = blockIdx.x;
    const int tid = threadIdx.x;
    for (int t = tid; t < 129; t += 256) rpl[t] = rp[g * 128 + t];
    __syncthreads();
    const int sG = rpl[0], eG = rpl[128];
    const bool ovf = (eG - sG) > 2048;

    if (tid < 128) {
        const int v = g * 128 + tid;
        const int s = rpl[tid], e = rpl[tid + 1];
        float edv = ed[v];
        float eself = lrelu(es[v] + edv, 0.2f);
        float m = eself;
        float lg[32];
        for (int i = s; i < e; i++) {
            float t = lrelu(es[col[i]] + edv, 0.2f);
            int k = i - s;
            if (k < 32) lg[k] = t;
            m = fmaxf(m, t);
        }
        float wv = __expf(eself - m);
        float den = wv;
        for (int i = s; i < e; i++) {
            int k = i - s;
            float t = (k < 32) ? lg[k] : lrelu(es[col[i]] + edv, 0.2f);
            float w = __expf(t - m);
            if (k < 32) lg[k] = w;
            den += w;
        }
        float inv = 1.f / den;
        for (int i = s; i < e; i++) {
            int k = i - s;
            float w = (k < 32) ? lg[k] : __expf(lrelu(es[col[i]] + edv, 0.2f) - m);
            f16 wh = (f16)(w * inv);
            int off = i - sG;
            if (off < 2048) ewl[off] = wh; else ewg[i] = wh;
        }
        wsl[tid] = wv * inv;
    }
    __syncthreads();

    const int idx = tid & 7;
    const int slot = tid >> 3;
    const f16x8* y8 = (const f16x8*)y;
    float acc[8];
#pragma unroll
    for (int j = 0; j < 8; j++) acc[j] = 0.f;

#pragma unroll
    for (int pass = 0; pass < 4; pass++) {
        const int v = g * 128 + pass * 32 + slot;
        float ws = wsl[pass * 32 + slot];
        f16x8 self = y8[(size_t)v * 8 + idx];
#pragma unroll
        for (int j = 0; j < 8; j++) acc[j] = fmaf(ws, (float)self[j], acc[j]);
    }

    if (!ovf) {
        int i = sG + slot;
        for (; i + 96 < eG; i += 128) {
            int o = i - sG;
            int u0 = col[i], u1 = col[i + 32], u2 = col[i + 64], u3 = col[i + 96];
            float w0 = (float)ewl[o], w1 = (float)ewl[o + 32], w2 = (float)ewl[o + 64], w3 = (float)ewl[o + 96];
            f16x8 a0 = y8[(size_t)u0 * 8 + idx];
            f16x8 a1 = y8[(size_t)u1 * 8 + idx];
            f16x8 a2 = y8[(size_t)u2 * 8 + idx];
            f16x8 a3 = y8[(size_t)u3 * 8 + idx];
#pragma unroll
            for (int j = 0; j < 8; j++)
                acc[j] = fmaf(w0, (float)a0[j], fmaf(w1, (float)a1[j], fmaf(w2, (float)a2[j], fmaf(w3, (float)a3[j], acc[j]))));
        }
        for (; i < eG; i += 32) {
            int u = col[i];
            float w = (float)ewl[i - sG];
            f16x8 a = y8[(size_t)u * 8 + idx];
#pragma unroll
            for (int j = 0; j < 8; j++) acc[j] = fmaf(w, (float)a[j], acc[j]);
        }
    } else {
        for (int i = sG + slot; i < eG; i += 32) {
            int o = i - sG;
            float w = (float)((o < 2048) ? ewl[o] : ewg[i]);
            f16x8 a = y8[(size_t)col[i] * 8 + idx];
#pragma unroll
            for (int j = 0; j < 8; j++) acc[j] = fmaf(w, (float)a[j], acc[j]);
        }
    }

#pragma unroll
    for (int j = 0; j < 8; j++) sred[slot * 68 + idx * 8 + j] = acc[j];
    __syncthreads();
    if (tid < 64) {
        float s2 = 0.f;
#pragma unroll
        for (int k = 0; k < 32; k++) s2 += sred[k * 68 + tid];
        pooled[(size_t)g * 64 + tid] = s2 * (1.f / 128.f) + bias[tid];
    }
}

// ---------------- fused cross-graph GAT + pooling + head (one block per graph) ----------------
__global__ __launch_bounds__(256) void cross_head_k(const float* __restrict__ pooled, const float* __restrict__ Wg2,
                                                    const float* __restrict__ asrc2, const float* __restrict__ adst2,
                                                    const float* __restrict__ bg2, const float* __restrict__ partials,
                                                    const float* __restrict__ Wl2, const float* __restrict__ bl2,
                                                    const float* __restrict__ Wl3, const float* __restrict__ bl3,
                                                    float* __restrict__ out) {
    __shared__ float pl[32 * 64];
    __shared__ float wl[64 * 64];
    __shared__ float xw2[32 * 64];
    __shared__ float es2[32], ed2[32];
    __shared__ float hsum[4][64];
    __shared__ float hbuf[64];
    const int b = blockIdx.x;
    const int tid = threadIdx.x;

    for (int t = tid; t < 2048; t += 256) pl[t] = pooled[(size_t)b * 2048 + t];
    for (int t = tid; t < 4096; t += 256) wl[t] = Wg2[t];
    __syncthreads();

    {   // xw2 = pl @ Wg2
        const int f = tid & 63;
        const int n0 = tid >> 6;
#pragma unroll
        for (int pass = 0; pass < 8; pass++) {
            int n = n0 + 4 * pass;
            float acc = 0.f;
#pragma unroll 8
            for (int k = 0; k < 64; k++) acc = fmaf(pl[n * 64 + k], wl[k * 64 + f], acc);
            xw2[n * 64 + f] = acc;
        }
    }
    __syncthreads();
    if (tid < 32) {
        float e1 = 0.f, e2 = 0.f;
#pragma unroll 8
        for (int k = 0; k < 64; k++) {
            float v = xw2[tid * 64 + k];
            e1 = fmaf(v, asrc2[k], e1);
            e2 = fmaf(v, adst2[k], e2);
        }
        es2[tid] = e1; ed2[tid] = e2;
    }
    __syncthreads();

    {   // dense cross-attention + mean over d
        const int f = tid & 63;
        const int dg = tid >> 6;  // 0..3
        float psum = 0.f;
#pragma unroll 1
        for (int pass = 0; pass < 8; pass++) {
            int d = dg + 4 * pass;
            float edd = ed2[d];
            float m = -1e30f;
#pragma unroll
            for (int s = 0; s < 32; s++) m = fmaxf(m, lrelu(es2[s] + edd, 0.2f));
            float den = 0.f, acc = 0.f;
#pragma unroll
            for (int s = 0; s < 32; s++) {
                float e = lrelu(es2[s] + edd, 0.2f);
                float w = __expf(e - m) * ((s == d) ? 1.f : 2.f);
                den += w;
                acc = fmaf(w, xw2[s * 64 + f], acc);
            }
            psum += acc / den;
        }
        hsum[dg][f] = psum;
    }
    __syncthreads();

    if (tid < 64) {
        const int f = tid;
        float hc = (hsum[0][f] + hsum[1][f] + hsum[2][f] + hsum[3][f]) * (1.f / 32.f) + bg2[f];
        float p = 0.f;
#pragma unroll
        for (int q = 0; q < 8; q++) p += partials[((size_t)b * 8 + q) * 64 + f];
        hbuf[f] = hc + p * (1.f / 256.f);
    }
    __syncthreads();
    if (tid < 64) {
        const int f = tid;
        float acc = bl2[f];
#pragma unroll 8
        for (int k = 0; k < 64; k++) acc = fmaf(hbuf[k], Wl2[k * 64 + f], acc);
        acc = lrelu(acc, 0.01f);
        float pr = acc * Wl3[f];
#pragma unroll
        for (int off = 32; off > 0; off >>= 1) pr += __shfl_down(pr, off, 64);
        if (f == 0) out[b] = 1.f / (1.f + __expf(-(pr + bl3[0])));
    }
}

// ---------------- fused conv branch (transposed f16 stages + dot2, 512 blocks) ----------------
__global__ __launch_bounds__(256) void conv_fused_k(
        const float* __restrict__ pts, const float* __restrict__ c1W, const float* __restrict__ c1b,
        const float* __restrict__ g1, const float* __restrict__ be1,
        const f16* __restrict__ w2p, const float* __restrict__ c2b,
        const float* __restrict__ g2, const float* __restrict__ be2,
        const f16* __restrict__ w3pc, const float* __restrict__ c3b,
        float* __restrict__ partials) {
    __shared__ __align__(16) float s0[3 * 264];
    __shared__ __align__(16) f16 s1T[132 * 32];
    __shared__ __align__(16) f16 s2T[66 * 64];
    __shared__ float sred[256];

    const int b = blockIdx.x >> 3;
    const int q = blockIdx.x & 7;
    const int tid = threadIdx.x;
    const float bnscale = 0.99999500003749968f;

    const int lo0 = 256 * q - 7;
    for (int t = tid; t < 3 * 263; t += 256) {
        int c = t / 263, j = t - c * 263;
        int p = lo0 + j;
        s0[c * 264 + j] = (p >= 0 && p < PP) ? pts[((size_t)b * 3 + c) * PP + p] : 0.f;
    }
    __syncthreads();

    {
        const int ch = tid & 31;
        const int j0 = tid >> 5;
        float wv[9];
        const float* wg = c1W + ch * 9;
#pragma unroll
        for (int t = 0; t < 9; t++) wv[t] = wg[t];
        const float bs = c1b[ch];
        const float gs = g1[ch] * bnscale;
        const float bt = be1[ch];
        const int lo1 = 128 * q - 3;
        for (int j = j0; j < 131; j += 8) {
            int p1 = lo1 + j;
            float v = 0.f;
            if (p1 >= 0 && p1 < 1024) {
                const float* x0 = s0 + 2 * j;
                float a0 = bs, a1 = 0.f, a2 = 0.f;
#pragma unroll
                for (int c = 0; c < 3; c++) {
                    float2 x01 = *(const float2*)(x0 + c * 264);
                    float x2v = x0[c * 264 + 2];
                    a0 = fmaf(x01.x, wv[c * 3 + 0], a0);
                    a1 = fmaf(x01.y, wv[c * 3 + 1], a1);
                    a2 = fmaf(x2v, wv[c * 3 + 2], a2);
                }
                float acc = a0 + a1 + a2;
                acc = lrelu(acc, 0.01f);
                v = fmaf(acc, gs, bt);
            }
            s1T[j * 32 + ch] = (f16)v;
        }
    }
    __syncthreads();

    {
        const int ch = tid & 63;
        const int jg = tid >> 6;
        unsigned wr[48];
        const uint4* wp = (const uint4*)(w2p + (size_t)ch * 96);
#pragma unroll
        for (int t = 0; t < 12; t++) {
            uint4 u = wp[t];
            wr[4 * t + 0] = u.x; wr[4 * t + 1] = u.y; wr[4 * t + 2] = u.z; wr[4 * t + 3] = u.w;
        }
        const float bs = c2b[ch];
        const float gs = g2[ch] * bnscale;
        const float bt = be2[ch];
        const int lo2v = 64 * q - 1;
        for (int j = jg; j < 65; j += 4) {
            float ak[3] = {bs, 0.f, 0.f};
#pragma unroll
            for (int k = 0; k < 3; k++) {
                const uint4* xp = (const uint4*)(s1T + (2 * j + k) * 32);
                uint4 x0 = xp[0], x1 = xp[1], x2 = xp[2], x3 = xp[3];
                float a = ak[k];
                a = dot2f(x0.x, wr[k * 16 + 0], a);
                a = dot2f(x0.y, wr[k * 16 + 1], a);
                a = dot2f(x0.z, wr[k * 16 + 2], a);
                a = dot2f(x0.w, wr[k * 16 + 3], a);
                a = dot2f(x1.x, wr[k * 16 + 4], a);
                a = dot2f(x1.y, wr[k * 16 + 5], a);
                a = dot2f(x1.z, wr[k * 16 + 6], a);
                a = dot2f(x1.w, wr[k * 16 + 7], a);
                a = dot2f(x2.x, wr[k * 16 + 8], a);
                a = dot2f(x2.y, wr[k * 16 + 9], a);
                a = dot2f(x2.z, wr[k * 16 + 10], a);
                a = dot2f(x2.w, wr[k * 16 + 11], a);
                a = dot2f(x3.x, wr[k * 16 + 12], a);
                a = dot2f(x3.y, wr[k * 16 + 13], a);
                a = dot2f(x3.z, wr[k * 16 + 14], a);
                a = dot2f(x3.w, wr[k * 16 + 15], a);
                ak[k] = a;
            }
            float acc = ak[0] + ak[1] + ak[2];
            int p2 = lo2v + j;
            float v = 0.f;
            if (p2 >= 0 && p2 < 512) v = fmaf(lrelu(acc, 0.01f), gs, bt);
            s2T[j * 64 + ch] = (f16)v;
        }
    }
    __syncthreads();

    {
        const int ch = tid & 63;
        const int jg = tid >> 6;
        unsigned wr[96];
        const uint4* wp = (const uint4*)(w3pc + (size_t)ch * 192);
#pragma unroll
        for (int t = 0; t < 24; t++) {
            uint4 u = wp[t];
            wr[4 * t + 0] = u.x; wr[4 * t + 1] = u.y; wr[4 * t + 2] = u.z; wr[4 * t + 3] = u.w;
        }
        const float bs = c3b[ch];
        float psum = 0.f;
        for (int j = jg; j < 32; j += 4) {
            float ak[3] = {bs, 0.f, 0.f};
#pragma unroll
            for (int k = 0; k < 3; k++) {
                const uint4* xp = (const uint4*)(s2T + (2 * j + k) * 64);
                float a = ak[k];
#pragma unroll
                for (int t = 0; t < 8; t++) {
                    uint4 xv = xp[t];
                    a = dot2f(xv.x, wr[k * 32 + 4 * t + 0], a);
                    a = dot2f(xv.y, wr[k * 32 + 4 * t + 1], a);
                    a = dot2f(xv.z, wr[k * 32 + 4 * t + 2], a);
                    a = dot2f(xv.w, wr[k * 32 + 4 * t + 3], a);
                }
                ak[k] = a;
            }
            psum += lrelu(ak[0] + ak[1] + ak[2], 0.01f);
        }
        sred[tid] = psum;
    }
    __syncthreads();
    if (tid < 64) {
        float s = sred[tid] + sred[tid + 64] + sred[tid + 128] + sred[tid + 192];
        partials[((size_t)b * 8 + q) * 64 + tid] = s;
    }
}

extern "C" void kernel_launch(void* const* d_in, const int* in_sizes, int n_in,
                              void* d_out, int out_size, void* d_ws, size_t ws_size,
                              hipStream_t stream) {
    const float* x = (const float*)d_in[0];
    const int* ei = (const int*)d_in[1];
    const float* points = (const float*)d_in[2];
    const float* W1 = (const float*)d_in[3];
    const float* b1 = (const float*)d_in[4];
    const float* W2 = (const float*)d_in[5];
    const float* b2 = (const float*)d_in[6];
    const float* W3 = (const float*)d_in[7];
    const float* b3 = (const float*)d_in[8];
    const float* Wg1 = (const float*)d_in[9];
    const float* asrc1 = (const float*)d_in[10];
    const float* adst1 = (const float*)d_in[11];
    const float* bg1 = (const float*)d_in[12];
    const float* Wg2 = (const float*)d_in[13];
    const float* asrc2 = (const float*)d_in[14];
    const float* adst2 = (const float*)d_in[15];
    const float* bg2 = (const float*)d_in[16];
    const float* c1W = (const float*)d_in[17];
    const float* c1b = (const float*)d_in[18];
    const float* g1 = (const float*)d_in[19];
    const float* be1 = (const float*)d_in[20];
    const float* c2W = (const float*)d_in[21];
    const float* c2b = (const float*)d_in[22];
    const float* g2 = (const float*)d_in[23];
    const float* be2 = (const float*)d_in[24];
    const float* c3W = (const float*)d_in[25];
    const float* c3b = (const float*)d_in[26];
    const float* Wl2 = (const float*)d_in[27];
    const float* bl2 = (const float*)d_in[28];
    const float* Wl3 = (const float*)d_in[29];
    const float* bl3 = (const float*)d_in[30];

    const int* src = ei;
    const int* dst = ei + EE;

    // ---- workspace carve-up ----
    char* w = (char*)d_ws;
    size_t off = 0;
    auto A = [&](size_t bytes) -> void* {
        void* p = w + off;
        off = (off + bytes + 255) & ~(size_t)255;
        return p;
    };
    int* colb = (int*)A((size_t)EE * 4);
    int* rp = (int*)A((size_t)(NN + 1) * 4);
    int* gcnt = (int*)A(NBUCK * 4);
    float* dinv = (float*)A((size_t)NN * 4);
    float* bufA = (float*)A((size_t)NN * 64 * 4);
    f16* bufH1 = (f16*)A((size_t)NN * 64 * 2);
    f16* bufH2 = (f16*)A((size_t)NN * 64 * 2);
    f16* ewi = (f16*)A((size_t)EE * 2);      // overflow backup only (practically never touched)
    float* es = (float*)A((size_t)NN * 4);
    float* edv = (float*)A((size_t)NN * 4);
    f16* w3p = (f16*)A(4096 * 2);
    f16* wgp = (f16*)A(4096 * 2);
    f16* wc2p = (f16*)A(64 * 96 * 2);
    f16* wc3p = (f16*)A(64 * 192 * 2);
    float* pooled = (float*)A((size_t)BB * CCROSS * 64 * 4);
    float* partials = (float*)A((size_t)BB * 8 * 64 * 4);

    unsigned* buckets = (unsigned*)bufA;   // aliases bufA; dead after CSR build

    // ---- CSR build (bucketed; scan folded into bucket_b) ----
    hipMemsetAsync(gcnt, 0, NBUCK * 4, stream);
    bucket_a_k<<<EE / 8192, 256, 0, stream>>>(src, dst, buckets, gcnt);
    bucket_b_k<<<NBUCK, 256, 0, stream>>>(buckets, gcnt, rp, dinv, colb);

    // ---- weight packing (single kernel) + points branch ----
    pack_all_k<<<104, 256, 0, stream>>>(W3, Wg1, c2W, c3W, w3p, wgp, wc2p, wc3p);
    conv_fused_k<<<BB * 8, 256, 0, stream>>>(points, c1W, c1b, g1, be1, wc2p, c2b, g2, be2, wc3p, c3b, partials);

    // ---- GCN 1/2 (fused agg+gemm), GCN3+GAT gemm (row-parallel gather fused into MFMA kernel) ----
    zprep_k<<<NN / 256, 256, 0, stream>>>(x, dinv, bufH1);                               // H1 = z1 [NN x 32h]
    fused_agg_gemm_k<19, 32, 0><<<NN / 64, 256, 0, stream>>>(bufH1, rp, colb, W1, dinv, b1, bufH2);  // H2 = z2
    fused_agg_gemm_k<32, 64, 1><<<NN / 64, 256, 0, stream>>>(bufH2, rp, colb, W2, dinv, b2, bufH1);  // H1 = z3
    gemm3_gat_k<<<NN / 64, 256, 0, stream>>>(bufH1, rp, colb, w3p, dinv, b3, wgp, asrc1, adst1,
                                             bufH2, es, edv);                            // H2 = xw, es/ed

    // ---- GAT 1: softmax + aggregation + piece-pooling, single kernel ----
    gat_aggw_pool_k<<<BB * CCROSS, 256, 0, stream>>>(bufH2, rp, colb, es, edv, bg1, ewi, pooled);

    // ---- cross GAT + pooling + head, single kernel ----
    cross_head_k<<<BB, 256, 0, stream>>>(pooled, Wg2, asrc2, adst2, bg2, partials,
                                         Wl2, bl2, Wl3, bl3, (float*)d_out);
}

// Round 8
// 454.459 us; speedup vs baseline: 1.2590x; 1.0164x over previous
//
#include <hip/hip_runtime.h>
#include <cstdint>
#include <cstddef>

#define NN 262144
#define EE 2097152
#define BB 64
#define CCROSS 32
#define PCC 128
#define PP 2048
#define NBUCK 256
#define BCAP 12288

typedef _Float16 f16;
typedef __attribute__((ext_vector_type(2))) _Float16 f16x2;
typedef __attribute__((ext_vector_type(4))) _Float16 f16x4;
typedef __attribute__((ext_vector_type(8))) _Float16 f16x8;
typedef __attribute__((ext_vector_type(4))) float f32x4;

static __device__ __forceinline__ float lrelu(float x, float s) { return x > 0.f ? x : s * x; }

#if __has_builtin(__builtin_amdgcn_fdot2)
static __device__ __forceinline__ float dot2f(unsigned x, unsigned w, float c) {
    return __builtin_amdgcn_fdot2(__builtin_bit_cast(f16x2, x), __builtin_bit_cast(f16x2, w), c, false);
}
#else
static __device__ __forceinline__ float dot2f(unsigned x, unsigned w, float c) {
    f16x2 a = __builtin_bit_cast(f16x2, x);
    f16x2 b = __builtin_bit_cast(f16x2, w);
    return fmaf((float)a[0], (float)b[0], fmaf((float)a[1], (float)b[1], c));
}
#endif

// ---------------- bucketed CSR build ----------------
__global__ __launch_bounds__(256) void bucket_a_k(const int* __restrict__ src, const int* __restrict__ dst,
                                                  unsigned* __restrict__ buckets, int* __restrict__ gcnt) {
    __shared__ int hist[NBUCK];
    __shared__ int base[NBUCK];
    __shared__ unsigned short rankbuf[8192];
    const int tid = threadIdx.x;
    const int e0 = blockIdx.x * 8192;
    hist[tid] = 0;
    __syncthreads();
    for (int i = tid; i < 8192; i += 256) {
        int d = dst[e0 + i];
        rankbuf[i] = (unsigned short)atomicAdd(&hist[d >> 10], 1);
    }
    __syncthreads();
    base[tid] = tid * BCAP + atomicAdd(&gcnt[tid], hist[tid]);
    __syncthreads();
    for (int i = tid; i < 8192; i += 256) {
        int s = src[e0 + i];
        int d = dst[e0 + i];
        int b = d >> 10;
        buckets[base[b] + rankbuf[i]] = ((unsigned)s << 10) | (unsigned)(d & 1023);
    }
}

// bucket_b with the global scan of gcnt folded in (each block redundantly scans 256 entries)
__global__ __launch_bounds__(256) void bucket_b_k(const unsigned* __restrict__ buckets, const int* __restrict__ gcnt,
                                                  int* __restrict__ rp,
                                                  float* __restrict__ dinv, int* __restrict__ col) {
    __shared__ int cnt[1024];
    __shared__ int scan[1024];
    __shared__ int wsum[256];
    const int b = blockIdx.x;
    const int tid = threadIdx.x;

    wsum[tid] = gcnt[tid];
    __syncthreads();
    for (int off = 1; off < 256; off <<= 1) {
        int t = (tid >= off) ? wsum[tid - off] : 0;
        __syncthreads();
        wsum[tid] += t;
        __syncthreads();
    }
    const int gb = wsum[b] - gcnt[b];
    if (b == 0 && tid == 0) rp[NN] = EE;

    int n = gcnt[b];
    if (n > BCAP) n = BCAP;
    const unsigned* eb = buckets + (size_t)b * BCAP;
    for (int i = tid; i < 1024; i += 256) cnt[i] = 0;
    __syncthreads();
    for (int i = tid; i < n; i += 256) atomicAdd(&cnt[eb[i] & 1023], 1);
    __syncthreads();
    int b4 = tid * 4;
    int c0 = cnt[b4], c1 = cnt[b4 + 1], c2 = cnt[b4 + 2], c3 = cnt[b4 + 3];
    int tsum = c0 + c1 + c2 + c3;
    wsum[tid] = tsum;
    __syncthreads();
    for (int off = 1; off < 256; off <<= 1) {
        int t = (tid >= off) ? wsum[tid - off] : 0;
        __syncthreads();
        wsum[tid] += t;
        __syncthreads();
    }
    int excl = wsum[tid] - tsum;
    scan[b4] = excl;
    scan[b4 + 1] = excl + c0;
    scan[b4 + 2] = excl + c0 + c1;
    scan[b4 + 3] = excl + c0 + c1 + c2;
    int vbase = b * 1024 + b4;
    rp[vbase + 0] = gb + scan[b4 + 0];
    rp[vbase + 1] = gb + scan[b4 + 1];
    rp[vbase + 2] = gb + scan[b4 + 2];
    rp[vbase + 3] = gb + scan[b4 + 3];
    dinv[vbase + 0] = rsqrtf((float)(c0 + 1));
    dinv[vbase + 1] = rsqrtf((float)(c1 + 1));
    dinv[vbase + 2] = rsqrtf((float)(c2 + 1));
    dinv[vbase + 3] = rsqrtf((float)(c3 + 1));
    __syncthreads();
    for (int i = tid; i < 1024; i += 256) cnt[i] = 0;
    __syncthreads();
    for (int i = tid; i < n; i += 256) {
        unsigned p = eb[i];
        int dl = p & 1023;
        int r = atomicAdd(&cnt[dl], 1);
        col[gb + scan[dl] + r] = (int)(p >> 10);
    }
}

// ---------------- z-prep ----------------
__global__ void zprep_k(const float* __restrict__ x, const float* __restrict__ dinv, f16* __restrict__ z) {
    int v = blockIdx.x * 256 + threadIdx.x;
    if (v >= NN) return;
    float dv = dinv[v];
    const float* xr = x + (size_t)v * 19;
    float vv[20];
#pragma unroll
    for (int k = 0; k < 19; k++) vv[k] = dv * xr[k];
    vv[19] = 0.f;
    f16x4* zr = (f16x4*)(z + (size_t)v * 32);
#pragma unroll
    for (int c = 0; c < 5; c++) {
        f16x4 t = {(f16)vv[4 * c], (f16)vv[4 * c + 1], (f16)vv[4 * c + 2], (f16)vv[4 * c + 3]};
        zr[c] = t;
    }
    f16x4 zz = {(f16)0.f, (f16)0.f, (f16)0.f, (f16)0.f};
#pragma unroll
    for (int c = 5; c < 8; c++) zr[c] = zz;
}

// ---------------- fused agg (64B fp16 rows) + gemm, wide-gather version ----------------
#define ZSTR1 36
template <int KINR, int KOUT, int ACT>
__global__ __launch_bounds__(256) void fused_agg_gemm_k(const f16* __restrict__ z, const int* __restrict__ rp,
                                                        const int* __restrict__ col, const float* __restrict__ Wg,
                                                        const float* __restrict__ dinv, const float* __restrict__ bias,
                                                        f16* __restrict__ zout) {
    constexpr int NO = KOUT / 4;
    __shared__ float Wl[32 * KOUT];
    __shared__ float zrow[64 * ZSTR1];
    const int tid = threadIdx.x;
    for (int i = tid; i < 32 * KOUT; i += 256) Wl[i] = (i < KINR * KOUT) ? Wg[i] : 0.f;

    const int r = tid >> 2;
    const int idx = tid & 3;
    const int v = blockIdx.x * 64 + r;
    const f16x8* z8 = (const f16x8*)z;
    f16x8 a = z8[(size_t)v * 4 + idx];
    float acc8[8];
#pragma unroll
    for (int j = 0; j < 8; j++) acc8[j] = (float)a[j];
    int st = rp[v], e = rp[v + 1];
    int i = st;
    for (; i + 4 <= e; i += 4) {
        int u0 = col[i], u1 = col[i + 1], u2 = col[i + 2], u3 = col[i + 3];
        f16x8 a0 = z8[(size_t)u0 * 4 + idx];
        f16x8 a1 = z8[(size_t)u1 * 4 + idx];
        f16x8 a2 = z8[(size_t)u2 * 4 + idx];
        f16x8 a3 = z8[(size_t)u3 * 4 + idx];
#pragma unroll
        for (int j = 0; j < 8; j++)
            acc8[j] += ((float)a0[j] + (float)a1[j]) + ((float)a2[j] + (float)a3[j]);
    }
    for (; i < e; i++) {
        f16x8 aa = z8[(size_t)col[i] * 4 + idx];
#pragma unroll
        for (int j = 0; j < 8; j++) acc8[j] += (float)aa[j];
    }
    float4 s0, s1;
    s0.x = acc8[0]; s0.y = acc8[1]; s0.z = acc8[2]; s0.w = acc8[3];
    s1.x = acc8[4]; s1.y = acc8[5]; s1.z = acc8[6]; s1.w = acc8[7];
    *(float4*)&zrow[r * ZSTR1 + idx * 8] = s0;
    *(float4*)&zrow[r * ZSTR1 + idx * 8 + 4] = s1;
    __syncthreads();

    float acc[NO];
#pragma unroll
    for (int j = 0; j < NO; j++) acc[j] = 0.f;
#pragma unroll 4
    for (int k = 0; k < 32; k++) {
        float zv = zrow[r * ZSTR1 + k];
        const float* wr = Wl + k * KOUT + NO * idx;
#pragma unroll
        for (int j = 0; j < NO; j++) acc[j] = fmaf(zv, wr[j], acc[j]);
    }
    float dv = dinv[v];
    f16 hv[NO];
#pragma unroll
    for (int j = 0; j < NO; j++) {
        float o = dv * acc[j] + bias[NO * idx + j];
        o = (ACT == 0) ? fmaxf(o, 0.f) : lrelu(o, 0.01f);
        hv[j] = (f16)(o * dv);
    }
    if constexpr (NO == 8) {
        f16x8 h = {hv[0], hv[1], hv[2], hv[3], hv[4], hv[5], hv[6], hv[7]};
        *(f16x8*)(zout + (size_t)v * KOUT + NO * idx) = h;
    } else {
        f16x8 h0 = {hv[0], hv[1], hv[2], hv[3], hv[4], hv[5], hv[6], hv[7]};
        f16x8 h1 = {hv[8], hv[9], hv[10], hv[11], hv[12], hv[13], hv[14], hv[15]};
        f16x8* yo = (f16x8*)(zout + (size_t)v * KOUT + NO * idx);
        yo[0] = h0; yo[1] = h1;
    }
}

// ---------------- pack all weights in one kernel ----------------
__global__ void pack_all_k(const float* __restrict__ W3, const float* __restrict__ Wg1,
                           const float* __restrict__ c2W, const float* __restrict__ c3W,
                           f16* __restrict__ w3p, f16* __restrict__ wgp,
                           f16* __restrict__ wc2p, f16* __restrict__ wc3p) {
    int o = blockIdx.x * 256 + threadIdx.x;
    if (o < 8192) {
        int oo = o & 4095;
        const float* W = (o < 4096) ? W3 : Wg1;
        f16* out = (o < 4096) ? w3p : wgp;
        int frag = oo >> 9;
        int kt = frag >> 2;
        int c = frag & 3;
        int idx = oo & 511;
        int l = idx >> 3;
        int j = idx & 7;
        int k = kt * 32 + ((l >> 4) << 3) + j;
        int n = 16 * c + (l & 15);
        out[oo] = (f16)W[k * 64 + n];
    } else if (o < 14336) {
        int oo = o - 8192;
        int ch = oo / 96, r = oo - ch * 96;
        int k = r >> 5, ci = r & 31;
        wc2p[oo] = (f16)c2W[ch * 96 + ci * 3 + k];
    } else if (o < 26624) {
        int oo = o - 14336;
        int ch = oo / 192, r = oo - ch * 192;
        int k = r >> 6, ci = r & 63;
        wc3p[oo] = (f16)c3W[ch * 192 + ci * 3 + k];
    }
}

// ---------------- fused: agg(z3) gather -> LDS; h3 = lrelu(dinv*(agg@W3)+b3); xw = h3@Wg1; es/ed ----------------
#define HSTR 72
__global__ __launch_bounds__(256) void gemm3_gat_k(const f16* __restrict__ y, const int* __restrict__ rp,
                                                   const int* __restrict__ col, const f16* __restrict__ w3p,
                                                   const float* __restrict__ dinv, const float* __restrict__ b3,
                                                   const f16* __restrict__ wgp, const float* __restrict__ av,
                                                   const float* __restrict__ ad, f16* __restrict__ xw,
                                                   float* __restrict__ es, float* __restrict__ ed) {
    __shared__ f16 zin[64 * HSTR];
    __shared__ f16 hh[64 * HSTR];
    const int tid = threadIdx.x;
    const int v0 = blockIdx.x * 64;
    {
        const int row = tid >> 2;
        const int idx = tid & 3;
        const int v = v0 + row;
        const f16x8* y8 = (const f16x8*)y;
        f16x8 s0 = y8[(size_t)v * 8 + idx * 2];
        f16x8 s1 = y8[(size_t)v * 8 + idx * 2 + 1];
        float acc[16];
#pragma unroll
        for (int j = 0; j < 8; j++) { acc[j] = (float)s0[j]; acc[8 + j] = (float)s1[j]; }
        int s = rp[v], e = rp[v + 1];
        int i = s;
        for (; i + 4 <= e; i += 4) {
            int u0 = col[i], u1 = col[i + 1], u2 = col[i + 2], u3 = col[i + 3];
            f16x8 a0 = y8[(size_t)u0 * 8 + idx * 2];
            f16x8 a1 = y8[(size_t)u0 * 8 + idx * 2 + 1];
            f16x8 b0 = y8[(size_t)u1 * 8 + idx * 2];
            f16x8 b1 = y8[(size_t)u1 * 8 + idx * 2 + 1];
            f16x8 c0 = y8[(size_t)u2 * 8 + idx * 2];
            f16x8 c1 = y8[(size_t)u2 * 8 + idx * 2 + 1];
            f16x8 d0 = y8[(size_t)u3 * 8 + idx * 2];
            f16x8 d1 = y8[(size_t)u3 * 8 + idx * 2 + 1];
#pragma unroll
            for (int j = 0; j < 8; j++) {
                acc[j] += ((float)a0[j] + (float)b0[j]) + ((float)c0[j] + (float)d0[j]);
                acc[8 + j] += ((float)a1[j] + (float)b1[j]) + ((float)c1[j] + (float)d1[j]);
            }
        }
        for (; i < e; i++) {
            int u = col[i];
            f16x8 a0 = y8[(size_t)u * 8 + idx * 2];
            f16x8 a1 = y8[(size_t)u * 8 + idx * 2 + 1];
#pragma unroll
            for (int j = 0; j < 8; j++) { acc[j] += (float)a0[j]; acc[8 + j] += (float)a1[j]; }
        }
        f16x8 o0, o1;
#pragma unroll
        for (int j = 0; j < 8; j++) { o0[j] = (f16)acc[j]; o1[j] = (f16)acc[8 + j]; }
        *(f16x8*)&zin[row * HSTR + idx * 16] = o0;
        *(f16x8*)&zin[row * HSTR + idx * 16 + 8] = o1;
    }
    __syncthreads();

    const int w = tid >> 6;
    const int l = tid & 63;
    const int m = l & 15;
    const int q = l >> 4;
    const int r0 = 16 * w;

    f32x4 acc0 = {0.f, 0.f, 0.f, 0.f}, acc1 = acc0, acc2 = acc0, acc3 = acc0;
#pragma unroll
    for (int kt = 0; kt < 2; kt++) {
        f16x8 afrag = *(const f16x8*)&zin[(r0 + m) * HSTR + kt * 32 + q * 8];
        f16x8 b0 = *(const f16x8*)&w3p[((kt * 4 + 0) << 9) + l * 8];
        f16x8 b1 = *(const f16x8*)&w3p[((kt * 4 + 1) << 9) + l * 8];
        f16x8 b2 = *(const f16x8*)&w3p[((kt * 4 + 2) << 9) + l * 8];
        f16x8 b3f = *(const f16x8*)&w3p[((kt * 4 + 3) << 9) + l * 8];
        acc0 = __builtin_amdgcn_mfma_f32_16x16x32_f16(afrag, b0, acc0, 0, 0, 0);
        acc1 = __builtin_amdgcn_mfma_f32_16x16x32_f16(afrag, b1, acc1, 0, 0, 0);
        acc2 = __builtin_amdgcn_mfma_f32_16x16x32_f16(afrag, b2, acc2, 0, 0, 0);
        acc3 = __builtin_amdgcn_mfma_f32_16x16x32_f16(afrag, b3f, acc3, 0, 0, 0);
    }
    {
        float dv0 = dinv[v0 + r0 + q * 4 + 0];
        float dv1 = dinv[v0 + r0 + q * 4 + 1];
        float dv2 = dinv[v0 + r0 + q * 4 + 2];
        float dv3 = dinv[v0 + r0 + q * 4 + 3];
#pragma unroll
        for (int c = 0; c < 4; c++) {
            const f32x4* ac = (c == 0) ? &acc0 : (c == 1) ? &acc1 : (c == 2) ? &acc2 : &acc3;
            float bb = b3[16 * c + m];
            hh[(r0 + q * 4 + 0) * HSTR + 16 * c + m] = (f16)lrelu(dv0 * (*ac)[0] + bb, 0.01f);
            hh[(r0 + q * 4 + 1) * HSTR + 16 * c + m] = (f16)lrelu(dv1 * (*ac)[1] + bb, 0.01f);
            hh[(r0 + q * 4 + 2) * HSTR + 16 * c + m] = (f16)lrelu(dv2 * (*ac)[2] + bb, 0.01f);
            hh[(r0 + q * 4 + 3) * HSTR + 16 * c + m] = (f16)lrelu(dv3 * (*ac)[3] + bb, 0.01f);
        }
    }
    __syncthreads();

    acc0 = (f32x4){0.f, 0.f, 0.f, 0.f}; acc1 = acc0; acc2 = acc0; acc3 = acc0;
#pragma unroll
    for (int kt = 0; kt < 2; kt++) {
        f16x8 afrag = *(const f16x8*)&hh[(r0 + m) * HSTR + kt * 32 + q * 8];
        f16x8 b0 = *(const f16x8*)&wgp[((kt * 4 + 0) << 9) + l * 8];
        f16x8 b1 = *(const f16x8*)&wgp[((kt * 4 + 1) << 9) + l * 8];
        f16x8 b2 = *(const f16x8*)&wgp[((kt * 4 + 2) << 9) + l * 8];
        f16x8 b3f = *(const f16x8*)&wgp[((kt * 4 + 3) << 9) + l * 8];
        acc0 = __builtin_amdgcn_mfma_f32_16x16x32_f16(afrag, b0, acc0, 0, 0, 0);
        acc1 = __builtin_amdgcn_mfma_f32_16x16x32_f16(afrag, b1, acc1, 0, 0, 0);
        acc2 = __builtin_amdgcn_mfma_f32_16x16x32_f16(afrag, b2, acc2, 0, 0, 0);
        acc3 = __builtin_amdgcn_mfma_f32_16x16x32_f16(afrag, b3f, acc3, 0, 0, 0);
    }
    {
        float e1[4] = {0.f, 0.f, 0.f, 0.f}, e2[4] = {0.f, 0.f, 0.f, 0.f};
#pragma unroll
        for (int c = 0; c < 4; c++) {
            const f32x4* ac = (c == 0) ? &acc0 : (c == 1) ? &acc1 : (c == 2) ? &acc2 : &acc3;
            float a1 = av[16 * c + m];
            float d1 = ad[16 * c + m];
#pragma unroll
            for (int reg = 0; reg < 4; reg++) {
                float g = (*ac)[reg];
                e1[reg] = fmaf(g, a1, e1[reg]);
                e2[reg] = fmaf(g, d1, e2[reg]);
                xw[(size_t)(v0 + r0 + q * 4 + reg) * 64 + 16 * c + m] = (f16)g;
            }
        }
#pragma unroll
        for (int reg = 0; reg < 4; reg++) {
            e1[reg] += __shfl_xor(e1[reg], 1); e1[reg] += __shfl_xor(e1[reg], 2);
            e1[reg] += __shfl_xor(e1[reg], 4); e1[reg] += __shfl_xor(e1[reg], 8);
            e2[reg] += __shfl_xor(e2[reg], 1); e2[reg] += __shfl_xor(e2[reg], 2);
            e2[reg] += __shfl_xor(e2[reg], 4); e2[reg] += __shfl_xor(e2[reg], 8);
        }
        if (m == 0) {
#pragma unroll
            for (int reg = 0; reg < 4; reg++) {
                es[v0 + r0 + q * 4 + reg] = e1[reg];
                ed[v0 + r0 + q * 4 + reg] = e2[reg];
            }
        }
    }
}

// ---------------- fused GAT softmax + edge-parallel aggregation + piece-mean pooling ----------------
// Phase A0 (all 256 threads): bulk edge-parallel stage twl[o] = es[col[sG+o]] (independent loads, L2-served).
// Phase A1 (128 threads, one dst-row each): softmax entirely from LDS twl -> ewl (f16) + wsl.
// Phase B: edge-parallel flat walk (32 slots x 8 feat-lanes), weights from LDS.
// twl aliases sred (dead until the final reduce). Overflow groups (>2048 edges; ~never)
// fall back to the fully-serial global-gather path.
__global__ __launch_bounds__(256) void gat_aggw_pool_k(const f16* __restrict__ y, const int* __restrict__ rp,
                                                       const int* __restrict__ col,
                                                       const float* __restrict__ es, const float* __restrict__ ed,
                                                       const float* __restrict__ bias, f16* __restrict__ ewg,
                                                       float* __restrict__ pooled) {
    __shared__ float sbuf[32 * 68];   // phase A: twl[2048]; phase C: sred[32*68]
    __shared__ f16 ewl[2048];
    __shared__ float wsl[128];
    __shared__ int rpl[129];
    float* twl = sbuf;
    float* sred = sbuf;
    const int g = blockIdx.x;
    const int tid = threadIdx.x;
    for (int t = tid; t < 129; t += 256) rpl[t] = rp[g * 128 + t];
    __syncthreads();
    const int sG = rpl[0], eG = rpl[128];
    const int nE = eG - sG;
    const bool ovf = nE > 2048;

    if (!ovf) {
        // A0: bulk stage of es[col[...]] for the whole group's edge range
        for (int o = tid; o < nE; o += 256) twl[o] = es[col[sG + o]];
        __syncthreads();
        // A1: per-row softmax from LDS
        if (tid < 128) {
            const int v = g * 128 + tid;
            const int s = rpl[tid], e = rpl[tid + 1];
            float edv = ed[v];
            float eself = lrelu(es[v] + edv, 0.2f);
            float m = eself;
            float lg[32];
            for (int i = s; i < e; i++) {
                float t = lrelu(twl[i - sG] + edv, 0.2f);
                int k = i - s;
                if (k < 32) lg[k] = t;
                m = fmaxf(m, t);
            }
            float wv = __expf(eself - m);
            float den = wv;
            for (int i = s; i < e; i++) {
                int k = i - s;
                float t = (k < 32) ? lg[k] : lrelu(twl[i - sG] + edv, 0.2f);
                float w = __expf(t - m);
                if (k < 32) lg[k] = w;
                den += w;
            }
            float inv = 1.f / den;
            for (int i = s; i < e; i++) {
                int k = i - s;
                float w = (k < 32) ? lg[k] : __expf(lrelu(twl[i - sG] + edv, 0.2f) - m);
                ewl[i - sG] = (f16)(w * inv);
            }
            wsl[tid] = wv * inv;
        }
    } else {
        // fallback: original serial global-gather softmax (never expected)
        if (tid < 128) {
            const int v = g * 128 + tid;
            const int s = rpl[tid], e = rpl[tid + 1];
            float edv = ed[v];
            float eself = lrelu(es[v] + edv, 0.2f);
            float m = eself;
            float lg[32];
            for (int i = s; i < e; i++) {
                float t = lrelu(es[col[i]] + edv, 0.2f);
                int k = i - s;
                if (k < 32) lg[k] = t;
                m = fmaxf(m, t);
            }
            float wv = __expf(eself - m);
            float den = wv;
            for (int i = s; i < e; i++) {
                int k = i - s;
                float t = (k < 32) ? lg[k] : lrelu(es[col[i]] + edv, 0.2f);
                float w = __expf(t - m);
                if (k < 32) lg[k] = w;
                den += w;
            }
            float inv = 1.f / den;
            for (int i = s; i < e; i++) {
                int k = i - s;
                float w = (k < 32) ? lg[k] : __expf(lrelu(es[col[i]] + edv, 0.2f) - m);
                f16 wh = (f16)(w * inv);
                int off = i - sG;
                if (off < 2048) ewl[off] = wh; else ewg[i] = wh;
            }
            wsl[tid] = wv * inv;
        }
    }
    __syncthreads();

    const int idx = tid & 7;
    const int slot = tid >> 3;
    const f16x8* y8 = (const f16x8*)y;
    float acc[8];
#pragma unroll
    for (int j = 0; j < 8; j++) acc[j] = 0.f;

#pragma unroll
    for (int pass = 0; pass < 4; pass++) {
        const int v = g * 128 + pass * 32 + slot;
        float ws = wsl[pass * 32 + slot];
        f16x8 self = y8[(size_t)v * 8 + idx];
#pragma unroll
        for (int j = 0; j < 8; j++) acc[j] = fmaf(ws, (float)self[j], acc[j]);
    }

    if (!ovf) {
        int i = sG + slot;
        for (; i + 96 < eG; i += 128) {
            int o = i - sG;
            int u0 = col[i], u1 = col[i + 32], u2 = col[i + 64], u3 = col[i + 96];
            float w0 = (float)ewl[o], w1 = (float)ewl[o + 32], w2 = (float)ewl[o + 64], w3 = (float)ewl[o + 96];
            f16x8 a0 = y8[(size_t)u0 * 8 + idx];
            f16x8 a1 = y8[(size_t)u1 * 8 + idx];
            f16x8 a2 = y8[(size_t)u2 * 8 + idx];
            f16x8 a3 = y8[(size_t)u3 * 8 + idx];
#pragma unroll
            for (int j = 0; j < 8; j++)
                acc[j] = fmaf(w0, (float)a0[j], fmaf(w1, (float)a1[j], fmaf(w2, (float)a2[j], fmaf(w3, (float)a3[j], acc[j]))));
        }
        for (; i < eG; i += 32) {
            int u = col[i];
            float w = (float)ewl[i - sG];
            f16x8 a = y8[(size_t)u * 8 + idx];
#pragma unroll
            for (int j = 0; j < 8; j++) acc[j] = fmaf(w, (float)a[j], acc[j]);
        }
    } else {
        for (int i = sG + slot; i < eG; i += 32) {
            int o = i - sG;
            float w = (float)((o < 2048) ? ewl[o] : ewg[i]);
            f16x8 a = y8[(size_t)col[i] * 8 + idx];
#pragma unroll
            for (int j = 0; j < 8; j++) acc[j] = fmaf(w, (float)a[j], acc[j]);
        }
    }
    __syncthreads();  // twl reads done; safe to reuse sbuf as sred

#pragma unroll
    for (int j = 0; j < 8; j++) sred[slot * 68 + idx * 8 + j] = acc[j];
    __syncthreads();
    if (tid < 64) {
        float s2 = 0.f;
#pragma unroll
        for (int k = 0; k < 32; k++) s2 += sred[k * 68 + tid];
        pooled[(size_t)g * 64 + tid] = s2 * (1.f / 128.f) + bias[tid];
    }
}

// ---------------- fused cross-graph GAT + pooling + head (one block per graph) ----------------
__global__ __launch_bounds__(256) void cross_head_k(const float* __restrict__ pooled, const float* __restrict__ Wg2,
                                                    const float* __restrict__ asrc2, const float* __restrict__ adst2,
                                                    const float* __restrict__ bg2, const float* __restrict__ partials,
                                                    const float* __restrict__ Wl2, const float* __restrict__ bl2,
                                                    const float* __restrict__ Wl3, const float* __restrict__ bl3,
                                                    float* __restrict__ out) {
    __shared__ float pl[32 * 64];
    __shared__ float wl[64 * 64];
    __shared__ float xw2[32 * 64];
    __shared__ float es2[32], ed2[32];
    __shared__ float hsum[4][64];
    __shared__ float hbuf[64];
    const int b = blockIdx.x;
    const int tid = threadIdx.x;

    for (int t = tid; t < 2048; t += 256) pl[t] = pooled[(size_t)b * 2048 + t];
    for (int t = tid; t < 4096; t += 256) wl[t] = Wg2[t];
    __syncthreads();

    {
        const int f = tid & 63;
        const int n0 = tid >> 6;
#pragma unroll
        for (int pass = 0; pass < 8; pass++) {
            int n = n0 + 4 * pass;
            float acc = 0.f;
#pragma unroll 8
            for (int k = 0; k < 64; k++) acc = fmaf(pl[n * 64 + k], wl[k * 64 + f], acc);
            xw2[n * 64 + f] = acc;
        }
    }
    __syncthreads();
    if (tid < 32) {
        float e1 = 0.f, e2 = 0.f;
#pragma unroll 8
        for (int k = 0; k < 64; k++) {
            float v = xw2[tid * 64 + k];
            e1 = fmaf(v, asrc2[k], e1);
            e2 = fmaf(v, adst2[k], e2);
        }
        es2[tid] = e1; ed2[tid] = e2;
    }
    __syncthreads();

    {
        const int f = tid & 63;
        const int dg = tid >> 6;
        float psum = 0.f;
#pragma unroll 1
        for (int pass = 0; pass < 8; pass++) {
            int d = dg + 4 * pass;
            float edd = ed2[d];
            float m = -1e30f;
#pragma unroll
            for (int s = 0; s < 32; s++) m = fmaxf(m, lrelu(es2[s] + edd, 0.2f));
            float den = 0.f, acc = 0.f;
#pragma unroll
            for (int s = 0; s < 32; s++) {
                float e = lrelu(es2[s] + edd, 0.2f);
                float w = __expf(e - m) * ((s == d) ? 1.f : 2.f);
                den += w;
                acc = fmaf(w, xw2[s * 64 + f], acc);
            }
            psum += acc / den;
        }
        hsum[dg][f] = psum;
    }
    __syncthreads();

    if (tid < 64) {
        const int f = tid;
        float hc = (hsum[0][f] + hsum[1][f] + hsum[2][f] + hsum[3][f]) * (1.f / 32.f) + bg2[f];
        float p = 0.f;
#pragma unroll
        for (int q = 0; q < 8; q++) p += partials[((size_t)b * 8 + q) * 64 + f];
        hbuf[f] = hc + p * (1.f / 256.f);
    }
    __syncthreads();
    if (tid < 64) {
        const int f = tid;
        float acc = bl2[f];
#pragma unroll 8
        for (int k = 0; k < 64; k++) acc = fmaf(hbuf[k], Wl2[k * 64 + f], acc);
        acc = lrelu(acc, 0.01f);
        float pr = acc * Wl3[f];
#pragma unroll
        for (int off = 32; off > 0; off >>= 1) pr += __shfl_down(pr, off, 64);
        if (f == 0) out[b] = 1.f / (1.f + __expf(-(pr + bl3[0])));
    }
}

// ---------------- fused conv branch (transposed f16 stages + dot2, 512 blocks) ----------------
__global__ __launch_bounds__(256) void conv_fused_k(
        const float* __restrict__ pts, const float* __restrict__ c1W, const float* __restrict__ c1b,
        const float* __restrict__ g1, const float* __restrict__ be1,
        const f16* __restrict__ w2p, const float* __restrict__ c2b,
        const float* __restrict__ g2, const float* __restrict__ be2,
        const f16* __restrict__ w3pc, const float* __restrict__ c3b,
        float* __restrict__ partials) {
    __shared__ __align__(16) float s0[3 * 264];
    __shared__ __align__(16) f16 s1T[132 * 32];
    __shared__ __align__(16) f16 s2T[66 * 64];
    __shared__ float sred[256];

    const int b = blockIdx.x >> 3;
    const int q = blockIdx.x & 7;
    const int tid = threadIdx.x;
    const float bnscale = 0.99999500003749968f;

    const int lo0 = 256 * q - 7;
    for (int t = tid; t < 3 * 263; t += 256) {
        int c = t / 263, j = t - c * 263;
        int p = lo0 + j;
        s0[c * 264 + j] = (p >= 0 && p < PP) ? pts[((size_t)b * 3 + c) * PP + p] : 0.f;
    }
    __syncthreads();

    {
        const int ch = tid & 31;
        const int j0 = tid >> 5;
        float wv[9];
        const float* wg = c1W + ch * 9;
#pragma unroll
        for (int t = 0; t < 9; t++) wv[t] = wg[t];
        const float bs = c1b[ch];
        const float gs = g1[ch] * bnscale;
        const float bt = be1[ch];
        const int lo1 = 128 * q - 3;
        for (int j = j0; j < 131; j += 8) {
            int p1 = lo1 + j;
            float v = 0.f;
            if (p1 >= 0 && p1 < 1024) {
                const float* x0 = s0 + 2 * j;
                float a0 = bs, a1 = 0.f, a2 = 0.f;
#pragma unroll
                for (int c = 0; c < 3; c++) {
                    float2 x01 = *(const float2*)(x0 + c * 264);
                    float x2v = x0[c * 264 + 2];
                    a0 = fmaf(x01.x, wv[c * 3 + 0], a0);
                    a1 = fmaf(x01.y, wv[c * 3 + 1], a1);
                    a2 = fmaf(x2v, wv[c * 3 + 2], a2);
                }
                float acc = a0 + a1 + a2;
                acc = lrelu(acc, 0.01f);
                v = fmaf(acc, gs, bt);
            }
            s1T[j * 32 + ch] = (f16)v;
        }
    }
    __syncthreads();

    {
        const int ch = tid & 63;
        const int jg = tid >> 6;
        unsigned wr[48];
        const uint4* wp = (const uint4*)(w2p + (size_t)ch * 96);
#pragma unroll
        for (int t = 0; t < 12; t++) {
            uint4 u = wp[t];
            wr[4 * t + 0] = u.x; wr[4 * t + 1] = u.y; wr[4 * t + 2] = u.z; wr[4 * t + 3] = u.w;
        }
        const float bs = c2b[ch];
        const float gs = g2[ch] * bnscale;
        const float bt = be2[ch];
        const int lo2v = 64 * q - 1;
        for (int j = jg; j < 65; j += 4) {
            float ak[3] = {bs, 0.f, 0.f};
#pragma unroll
            for (int k = 0; k < 3; k++) {
                const uint4* xp = (const uint4*)(s1T + (2 * j + k) * 32);
                uint4 x0 = xp[0], x1 = xp[1], x2 = xp[2], x3 = xp[3];
                float a = ak[k];
                a = dot2f(x0.x, wr[k * 16 + 0], a);
                a = dot2f(x0.y, wr[k * 16 + 1], a);
                a = dot2f(x0.z, wr[k * 16 + 2], a);
                a = dot2f(x0.w, wr[k * 16 + 3], a);
                a = dot2f(x1.x, wr[k * 16 + 4], a);
                a = dot2f(x1.y, wr[k * 16 + 5], a);
                a = dot2f(x1.z, wr[k * 16 + 6], a);
                a = dot2f(x1.w, wr[k * 16 + 7], a);
                a = dot2f(x2.x, wr[k * 16 + 8], a);
                a = dot2f(x2.y, wr[k * 16 + 9], a);
                a = dot2f(x2.z, wr[k * 16 + 10], a);
                a = dot2f(x2.w, wr[k * 16 + 11], a);
                a = dot2f(x3.x, wr[k * 16 + 12], a);
                a = dot2f(x3.y, wr[k * 16 + 13], a);
                a = dot2f(x3.z, wr[k * 16 + 14], a);
                a = dot2f(x3.w, wr[k * 16 + 15], a);
                ak[k] = a;
            }
            float acc = ak[0] + ak[1] + ak[2];
            int p2 = lo2v + j;
            float v = 0.f;
            if (p2 >= 0 && p2 < 512) v = fmaf(lrelu(acc, 0.01f), gs, bt);
            s2T[j * 64 + ch] = (f16)v;
        }
    }
    __syncthreads();

    {
        const int ch = tid & 63;
        const int jg = tid >> 6;
        unsigned wr[96];
        const uint4* wp = (const uint4*)(w3pc + (size_t)ch * 192);
#pragma unroll
        for (int t = 0; t < 24; t++) {
            uint4 u = wp[t];
            wr[4 * t + 0] = u.x; wr[4 * t + 1] = u.y; wr[4 * t + 2] = u.z; wr[4 * t + 3] = u.w;
        }
        const float bs = c3b[ch];
        float psum = 0.f;
        for (int j = jg; j < 32; j += 4) {
            float ak[3] = {bs, 0.f, 0.f};
#pragma unroll
            for (int k = 0; k < 3; k++) {
                const uint4* xp = (const uint4*)(s2T + (2 * j + k) * 64);
                float a = ak[k];
#pragma unroll
                for (int t = 0; t < 8; t++) {
                    uint4 xv = xp[t];
                    a = dot2f(xv.x, wr[k * 32 + 4 * t + 0], a);
                    a = dot2f(xv.y, wr[k * 32 + 4 * t + 1], a);
                    a = dot2f(xv.z, wr[k * 32 + 4 * t + 2], a);
                    a = dot2f(xv.w, wr[k * 32 + 4 * t + 3], a);
                }
                ak[k] = a;
            }
            psum += lrelu(ak[0] + ak[1] + ak[2], 0.01f);
        }
        sred[tid] = psum;
    }
    __syncthreads();
    if (tid < 64) {
        float s = sred[tid] + sred[tid + 64] + sred[tid + 128] + sred[tid + 192];
        partials[((size_t)b * 8 + q) * 64 + tid] = s;
    }
}

extern "C" void kernel_launch(void* const* d_in, const int* in_sizes, int n_in,
                              void* d_out, int out_size, void* d_ws, size_t ws_size,
                              hipStream_t stream) {
    const float* x = (const float*)d_in[0];
    const int* ei = (const int*)d_in[1];
    const float* points = (const float*)d_in[2];
    const float* W1 = (const float*)d_in[3];
    const float* b1 = (const float*)d_in[4];
    const float* W2 = (const float*)d_in[5];
    const float* b2 = (const float*)d_in[6];
    const float* W3 = (const float*)d_in[7];
    const float* b3 = (const float*)d_in[8];
    const float* Wg1 = (const float*)d_in[9];
    const float* asrc1 = (const float*)d_in[10];
    const float* adst1 = (const float*)d_in[11];
    const float* bg1 = (const float*)d_in[12];
    const float* Wg2 = (const float*)d_in[13];
    const float* asrc2 = (const float*)d_in[14];
    const float* adst2 = (const float*)d_in[15];
    const float* bg2 = (const float*)d_in[16];
    const float* c1W = (const float*)d_in[17];
    const float* c1b = (const float*)d_in[18];
    const float* g1 = (const float*)d_in[19];
    const float* be1 = (const float*)d_in[20];
    const float* c2W = (const float*)d_in[21];
    const float* c2b = (const float*)d_in[22];
    const float* g2 = (const float*)d_in[23];
    const float* be2 = (const float*)d_in[24];
    const float* c3W = (const float*)d_in[25];
    const float* c3b = (const float*)d_in[26];
    const float* Wl2 = (const float*)d_in[27];
    const float* bl2 = (const float*)d_in[28];
    const float* Wl3 = (const float*)d_in[29];
    const float* bl3 = (const float*)d_in[30];

    const int* src = ei;
    const int* dst = ei + EE;

    // ---- workspace carve-up ----
    char* w = (char*)d_ws;
    size_t off = 0;
    auto A = [&](size_t bytes) -> void* {
        void* p = w + off;
        off = (off + bytes + 255) & ~(size_t)255;
        return p;
    };
    int* colb = (int*)A((size_t)EE * 4);
    int* rp = (int*)A((size_t)(NN + 1) * 4);
    int* gcnt = (int*)A(NBUCK * 4);
    float* dinv = (float*)A((size_t)NN * 4);
    float* bufA = (float*)A((size_t)NN * 64 * 4);
    f16* bufH1 = (f16*)A((size_t)NN * 64 * 2);
    f16* bufH2 = (f16*)A((size_t)NN * 64 * 2);
    f16* ewi = (f16*)A((size_t)EE * 2);      // overflow backup only (practically never touched)
    float* es = (float*)A((size_t)NN * 4);
    float* edv = (float*)A((size_t)NN * 4);
    f16* w3p = (f16*)A(4096 * 2);
    f16* wgp = (f16*)A(4096 * 2);
    f16* wc2p = (f16*)A(64 * 96 * 2);
    f16* wc3p = (f16*)A(64 * 192 * 2);
    float* pooled = (float*)A((size_t)BB * CCROSS * 64 * 4);
    float* partials = (float*)A((size_t)BB * 8 * 64 * 4);

    unsigned* buckets = (unsigned*)bufA;   // aliases bufA; dead after CSR build

    // ---- CSR build (bucketed; scan folded into bucket_b) ----
    hipMemsetAsync(gcnt, 0, NBUCK * 4, stream);
    bucket_a_k<<<EE / 8192, 256, 0, stream>>>(src, dst, buckets, gcnt);
    bucket_b_k<<<NBUCK, 256, 0, stream>>>(buckets, gcnt, rp, dinv, colb);

    // ---- weight packing (single kernel) + points branch ----
    pack_all_k<<<104, 256, 0, stream>>>(W3, Wg1, c2W, c3W, w3p, wgp, wc2p, wc3p);
    conv_fused_k<<<BB * 8, 256, 0, stream>>>(points, c1W, c1b, g1, be1, wc2p, c2b, g2, be2, wc3p, c3b, partials);

    // ---- GCN 1/2 (fused agg+gemm), GCN3+GAT gemm (row-parallel gather fused into MFMA kernel) ----
    zprep_k<<<NN / 256, 256, 0, stream>>>(x, dinv, bufH1);                               // H1 = z1 [NN x 32h]
    fused_agg_gemm_k<19, 32, 0><<<NN / 64, 256, 0, stream>>>(bufH1, rp, colb, W1, dinv, b1, bufH2);  // H2 = z2
    fused_agg_gemm_k<32, 64, 1><<<NN / 64, 256, 0, stream>>>(bufH2, rp, colb, W2, dinv, b2, bufH1);  // H1 = z3
    gemm3_gat_k<<<NN / 64, 256, 0, stream>>>(bufH1, rp, colb, w3p, dinv, b3, wgp, asrc1, adst1,
                                             bufH2, es, edv);                            // H2 = xw, es/ed

    // ---- GAT 1: softmax + aggregation + piece-pooling, single kernel ----
    gat_aggw_pool_k<<<BB * CCROSS, 256, 0, stream>>>(bufH2, rp, colb, es, edv, bg1, ewi, pooled);

    // ---- cross GAT + pooling + head, single kernel ----
    cross_head_k<<<BB, 256, 0, stream>>>(pooled, Wg2, asrc2, adst2, bg2, partials,
                                         Wl2, bl2, Wl3, bl3, (float*)d_out);
}